// Round 2
// baseline (2760.109 us; speedup 1.0000x reference)
//
#include <hip/hip_runtime.h>
#include <hip/hip_bf16.h>

typedef short v8s __attribute__((ext_vector_type(8)));
typedef float v4f __attribute__((ext_vector_type(4)));

#define T_ 512

__device__ __forceinline__ unsigned short f2bf(float f){
  unsigned int u = __builtin_bit_cast(unsigned int, f);
  unsigned int r = (u + 0x7fffu + ((u>>16)&1u)) >> 16;
  return (unsigned short)r;
}
__device__ __forceinline__ float b2f(unsigned short u){
  unsigned int x = ((unsigned int)u)<<16;
  return __builtin_bit_cast(float, x);
}
// custom e4m3 codec (matches HW e4m3fn for normals; flushes denormal encode)
__device__ __forceinline__ unsigned char f2e4m3(float f){
  unsigned u = __builtin_bit_cast(unsigned, f);
  unsigned s = (u>>24)&0x80u;
  unsigned a = u & 0x7fffffffu;
  unsigned m = a + 0x7ffffu + ((a>>20)&1u);   // RNE at bit 20
  int v = (int)(m>>20) - 960;                  // 120<<3 (bias shift)
  v = v<0?0:(v>126?126:v);
  return (unsigned char)(s|(unsigned)v);
}
__device__ __forceinline__ float e4m3f(unsigned b){
  unsigned v = b & 0x7fu;
  unsigned bits = ((b&0x80u)<<24) | (v? ((v+960u)<<20) : 0u);
  return __builtin_bit_cast(float, bits);
}
__device__ __forceinline__ unsigned gbyte(uint2 v, int i){
  return ((i<4)? (v.x>>(i*8)) : (v.y>>((i-4)*8))) & 0xffu;
}
__device__ __forceinline__ float sigm(float x){ return 1.f/(1.f + __expf(-x)); }
__device__ __forceinline__ float tanh_f(float x){
  float ax = fabsf(x);
  float e  = __expf(2.f*ax);
  float r  = 1.f - 2.f/(e+1.f);
  return copysignf(r, x);
}

// bf16 MFMA B-fragment-major layout for Wih (both dirs stacked: Ntot=2048)
// out[(kt*ntiles + ntile)*64 + lane] (8 shorts) = W[n=ntile*16+(lane&15)][kt*32+(lane>>4)*8+e]
__global__ __launch_bounds__(256) void prep_frag_k(
    const float* __restrict__ Wa, const float* __restrict__ Wb,
    unsigned short* __restrict__ out, int Ntot)
{
  int idx = blockIdx.x*256 + threadIdx.x;
  int lane = idx & 63;
  int t2 = idx >> 6;
  int ntiles = Ntot >> 4;
  int ntile = t2 % ntiles;
  int kt = t2 / ntiles;
  if (kt >= 8) return;
  int n  = ntile*16 + (lane & 15);
  int ks = lane >> 4;
  const float* src = (n < 1024) ? (Wa + (size_t)n*256) : (Wb + (size_t)(n-1024)*256);
  int k0 = kt*32 + ks*8;
  unsigned short* d = out + (size_t)idx*8;
  #pragma unroll
  for (int e=0;e<8;++e) d[e] = f2bf(src[k0+e]);
}

// fp8 MFMA B-fragments for Whh (2 dirs): out[((dir*8+kt)*64+ntile)*64+lane] (8 bytes)
__global__ __launch_bounds__(256) void prep_whh8_k(
    const float* __restrict__ Wf, const float* __restrict__ Wb,
    unsigned char* __restrict__ out)
{
  int idx = blockIdx.x*256 + threadIdx.x;      // 65536 threads
  int lane = idx & 63;
  int t2 = idx >> 6;
  int ntile = t2 & 63;
  int kt = (t2>>6) & 7;
  int dir = t2 >> 9;
  const float* W = dir ? Wb : Wf;
  int n = ntile*16 + (lane&15);
  int k0 = kt*32 + (lane>>4)*8;
  unsigned lo=0, hi=0;
  #pragma unroll
  for (int e=0;e<4;++e) lo |= ((unsigned)f2e4m3(W[(size_t)n*256 + k0 + e])) << (8*e);
  #pragma unroll
  for (int e=0;e<4;++e) hi |= ((unsigned)f2e4m3(W[(size_t)n*256 + k0 + 4 + e])) << (8*e);
  *(uint2*)(out + (size_t)idx*8) = make_uint2(lo, hi);
}

// xw = x @ [Wih_f; Wih_b]^T (bf16 MFMA), output fp8 in lane-permuted layout:
// xw[(dir*65536+m)*1024 + wv*128 + lr*8 + (q*2+sv)]
// waves split the N dim (each wave owns wv = w, w+4) -> B-frags read once per block.
__global__ __launch_bounds__(256) void xw_gemm_k(
    const int* __restrict__ sent, const float* __restrict__ emb,
    const unsigned short* __restrict__ wihg, const int* __restrict__ lens,
    unsigned char* __restrict__ xw)
{
  int mt = blockIdx.x;                       // 64 rows each
  if (((mt&7)<<6) >= lens[mt>>3]) return;    // tile fully beyond len
  __shared__ unsigned short A[64][264];      // bf16 x-rows, 16B-aligned stride
  int tid = threadIdx.x;
  {
    int r = tid>>2, q = tid&3;
    int tok = sent[mt*64 + r];
    const float4* s = (const float4*)(emb + (size_t)tok*256 + q*64);
    unsigned short* drow = &A[r][q*64];
    #pragma unroll
    for (int cc=0; cc<16; ++cc){
      float4 v = s[cc];
      uint2 o;
      o.x = (unsigned)f2bf(v.x) | ((unsigned)f2bf(v.y)<<16);
      o.y = (unsigned)f2bf(v.z) | ((unsigned)f2bf(v.w)<<16);
      *(uint2*)(drow + cc*4) = o;
    }
  }
  __syncthreads();
  int w = tid>>6, lane = tid&63, lr = lane&15, lq = lane>>4;
  #pragma unroll 1
  for (int p=0;p<2;++p){
    int wv = w + p*4;
    #pragma unroll 1
    for (int dn=0;dn<2;++dn){
      v4f acc[8][4];
      #pragma unroll
      for (int e=0;e<8;++e)
        #pragma unroll
        for (int m=0;m<4;++m) acc[e][m] = (v4f){0.f,0.f,0.f,0.f};
      #pragma unroll
      for (int kt=0;kt<8;++kt){
        v8s a0 = *(const v8s*)(&A[ 0+lr][kt*32 + lq*8]);
        v8s a1 = *(const v8s*)(&A[16+lr][kt*32 + lq*8]);
        v8s a2 = *(const v8s*)(&A[32+lr][kt*32 + lq*8]);
        v8s a3 = *(const v8s*)(&A[48+lr][kt*32 + lq*8]);
        #pragma unroll
        for (int e=0;e<8;++e){
          int ntile = dn*64 + (e>>1)*16 + wv*2 + (e&1);
          v8s bfr = *(const v8s*)(wihg + ((size_t)(kt*128 + ntile)*64 + lane)*8);
          acc[e][0] = __builtin_amdgcn_mfma_f32_16x16x32_bf16(a0, bfr, acc[e][0], 0,0,0);
          acc[e][1] = __builtin_amdgcn_mfma_f32_16x16x32_bf16(a1, bfr, acc[e][1], 0,0,0);
          acc[e][2] = __builtin_amdgcn_mfma_f32_16x16x32_bf16(a2, bfr, acc[e][2], 0,0,0);
          acc[e][3] = __builtin_amdgcn_mfma_f32_16x16x32_bf16(a3, bfr, acc[e][3], 0,0,0);
        }
      }
      #pragma unroll
      for (int m=0;m<4;++m){
        #pragma unroll
        for (int j=0;j<4;++j){
          int mr = mt*64 + m*16 + lq*4 + j;
          unsigned lo=0, hi=0;
          #pragma unroll
          for (int e=0;e<4;++e) lo |= ((unsigned)f2e4m3(acc[e  ][m][j])) << (8*e);
          #pragma unroll
          for (int e=0;e<4;++e) hi |= ((unsigned)f2e4m3(acc[4+e][m][j])) << (8*e);
          *(uint2*)(xw + ((size_t)dn*65536 + mr)*1024 + wv*128 + lr*8) = make_uint2(lo, hi);
        }
      }
    }
  }
}

// Recurrence: 16 blocks x 512 threads; block = (dir, 16 sequences).
// Whh fp8 fully VGPR-resident (128 regs/lane); h fp8 in LDS; fp8 MFMA.
__global__ __launch_bounds__(512,2) void lstm_k(
    const unsigned char* __restrict__ xw,
    const unsigned char* __restrict__ whh8,
    const float* __restrict__ bfv, const float* __restrict__ bbv,
    const int* __restrict__ lens,
    unsigned char* __restrict__ hout)
{
  int bid = blockIdx.x, dir = bid>>3, grp = bid&7;
  int tid = threadIdx.x, w = tid>>6, lane = tid&63, lr = lane&15, lq = lane>>4;
  __shared__ unsigned char hbuf[16][264];    // fp8 h, stride 264 (8B-aligned rows)
  __shared__ int tmax_s;
  for (int i=tid;i<16*264;i+=512) ((unsigned char*)hbuf)[i]=0;
  if (tid==0){
    int mx=0;
    for (int i=0;i<16;++i){ int l = lens[grp*16+i]; mx = l>mx? l:mx; }
    tmax_s = mx;
  }
  // Whh fragments into registers: wave w owns ntile = q*16 + w*2 + s
  long long wreg[64];
  const unsigned char* wb = whh8 + (size_t)dir*262144;
  #pragma unroll
  for (int kt=0;kt<8;++kt){
    #pragma unroll
    for (int nt=0;nt<8;++nt){
      int ntile = (nt>>1)*16 + w*2 + (nt&1);
      wreg[kt*8+nt] = *(const long long*)(wb + ((size_t)(kt*64 + ntile)*64 + lane)*8);
    }
  }
  const float* bb = dir ? bbv : bfv;
  float bias[4][2];
  #pragma unroll
  for (int q=0;q<4;++q){
    bias[q][0] = bb[q*256 + w*32 + lr];
    bias[q][1] = bb[q*256 + w*32 + 16 + lr];
  }
  int len_[4];
  #pragma unroll
  for (int j=0;j<4;++j) len_[j] = lens[grp*16 + lq*4 + j];
  float c[4][2] = {{0.f,0.f},{0.f,0.f},{0.f,0.f},{0.f,0.f}};
  const size_t dbase = (size_t)dir*65536;
  __syncthreads();
  int tmax = tmax_s;
  for (int t=0; t<tmax; ++t){
    uint2 xv[4];
    #pragma unroll
    for (int j=0;j<4;++j){
      int ln = len_[j];
      int te = (dir && t<ln) ? (ln-1-t) : t;
      xv[j] = *(const uint2*)(xw + (dbase + (size_t)(grp*16+lq*4+j)*T_ + te)*1024
                              + w*128 + lr*8);
    }
    v4f acc[8];
    #pragma unroll
    for (int nt=0;nt<8;++nt) acc[nt] = (v4f){0.f,0.f,0.f,0.f};
    #pragma unroll
    for (int kt=0;kt<8;++kt){
      long long a = *(const long long*)(&hbuf[lr][kt*32 + lq*8]);
      #pragma unroll
      for (int nt=0;nt<8;++nt)
        acc[nt] = __builtin_amdgcn_mfma_f32_16x16x32_fp8_fp8(a, wreg[kt*8+nt], acc[nt], 0,0,0);
    }
    __syncthreads();   // A-frag reads done before h rewrite
    #pragma unroll
    for (int j=0;j<4;++j){
      int ln = len_[j];
      bool valid = t < ln;
      int bseq = grp*16 + lq*4 + j;
      int pos = (dir && valid) ? (ln-1-t) : t;
      unsigned char* ho = hout + (dbase + (size_t)bseq*T_ + pos)*256;
      #pragma unroll
      for (int s=0;s<2;++s){
        int col = w*32 + s*16 + lr;
        float gi = acc[0+s][j] + e4m3f(gbyte(xv[j], 0+s)) + bias[0][s];
        float gf = acc[2+s][j] + e4m3f(gbyte(xv[j], 2+s)) + bias[1][s];
        float gg = acc[4+s][j] + e4m3f(gbyte(xv[j], 4+s)) + bias[2][s];
        float go = acc[6+s][j] + e4m3f(gbyte(xv[j], 6+s)) + bias[3][s];
        float iv = sigm(gi), fv = sigm(gf), gv = tanh_f(gg), ov = sigm(go);
        float cn = fv*c[j][s] + iv*gv;
        float hn = ov*tanh_f(cn);
        unsigned char hw8;
        if (valid){ c[j][s] = cn; unsigned char h8 = f2e4m3(hn);
                    hbuf[lq*4+j][col] = h8; hw8 = h8; }
        else hw8 = 0;
        ho[col] = hw8;
      }
    }
    __syncthreads();
  }
}

// em = [h_f, h_b] @ Wout^T + b_out (only t < len); hout is fp8
__global__ __launch_bounds__(256) void em_k(
    const unsigned char* __restrict__ hout,
    const float* __restrict__ Wout, const float* __restrict__ bout,
    const int* __restrict__ lens,
    float* __restrict__ em)
{
  __shared__ float Ws[9*512];
  for (int i=threadIdx.x;i<9*512;i+=256) Ws[i] = Wout[i];
  __syncthreads();
  int m = blockIdx.x*256 + threadIdx.x;
  int b = m>>9, t = m&511;
  if (t >= lens[b]) return;
  const unsigned char* hf = hout + (size_t)m*256;
  const unsigned char* hb = hout + ((size_t)65536 + m)*256;
  float a[9];
  #pragma unroll
  for (int k=0;k<9;++k) a[k] = bout[k];
  for (int cc=0; cc<256; cc+=16){
    uint4 vf = *(const uint4*)(hf+cc);
    uint4 vb = *(const uint4*)(hb+cc);
    const unsigned char* pf = (const unsigned char*)&vf;
    const unsigned char* pb = (const unsigned char*)&vb;
    float xf[16], xb[16];
    #pragma unroll
    for (int e=0;e<16;++e){ xf[e] = e4m3f(pf[e]); xb[e] = e4m3f(pb[e]); }
    #pragma unroll
    for (int k=0;k<9;++k){
      float s=a[k];
      #pragma unroll
      for (int e=0;e<16;++e) s += xf[e]*Ws[k*512+cc+e] + xb[e]*Ws[k*512+256+cc+e];
      a[k]=s;
    }
  }
  float* d = em + (size_t)m*9;
  #pragma unroll
  for (int k=0;k<9;++k) d[k]=a[k];
}

// CRF: one wave per sequence.
__global__ __launch_bounds__(256) void crf_k(
    const float* __restrict__ em, const int* __restrict__ tags,
    const int* __restrict__ lens, const float* __restrict__ startv,
    const float* __restrict__ endv, const float* __restrict__ trans,
    float* __restrict__ out)
{
  int wid = blockIdx.x*4 + (threadIdx.x>>6);
  int lane = threadIdx.x & 63;
  const float* e = em + (size_t)wid*T_*9;
  const int* tg = tags + (size_t)wid*T_;
  int L = lens[wid];
  float p = 0.f;
  for (int t = 1+lane; t < L; t += 64)
    p += trans[tg[t-1]*9 + tg[t]] + e[(size_t)t*9 + tg[t]];
  if (lane==0) p += startv[tg[0]] + e[tg[0]] + endv[tg[L-1]];
  #pragma unroll
  for (int off=32; off; off>>=1) p += __shfl_xor(p, off, 64);
  float tcol[9];
  #pragma unroll
  for (int i=0;i<9;++i) tcol[i] = (lane<9) ? trans[i*9 + lane] : 0.f;
  float alpha = (lane<9) ? (startv[lane] + e[lane]) : -1e30f;
  for (int t=1; t<L; ++t){
    float vs[9]; float mx = -1e30f;
    #pragma unroll
    for (int i=0;i<9;++i){
      float ai = __shfl(alpha, i, 64);
      vs[i] = ai + tcol[i];
      mx = fmaxf(mx, vs[i]);
    }
    float s = 0.f;
    #pragma unroll
    for (int i=0;i<9;++i) s += __expf(vs[i]-mx);
    float na = mx + __logf(s) + ((lane<9)? e[(size_t)t*9+lane] : 0.f);
    alpha = (lane<9) ? na : -1e30f;
  }
  float v = (lane<9) ? (alpha + endv[lane]) : -1e30f;
  float mx = v;
  #pragma unroll
  for (int off=32; off; off>>=1) mx = fmaxf(mx, __shfl_xor(mx, off, 64));
  float s = __expf(v-mx);
  #pragma unroll
  for (int off=32; off; off>>=1) s += __shfl_xor(s, off, 64);
  float logZ = mx + __logf(s);
  if (lane==0) atomicAdd(out, p - logZ);
}

extern "C" void kernel_launch(void* const* d_in, const int* in_sizes, int n_in,
                              void* d_out, int out_size, void* d_ws, size_t ws_size,
                              hipStream_t stream)
{
  const int*   sent  = (const int*)d_in[0];
  const int*   tags  = (const int*)d_in[1];
  const int*   lens  = (const int*)d_in[2];
  const float* emb   = (const float*)d_in[3];
  const float* Wih_f = (const float*)d_in[4];
  const float* Whh_f = (const float*)d_in[5];
  const float* b_f   = (const float*)d_in[6];
  const float* Wih_b = (const float*)d_in[7];
  const float* Whh_b = (const float*)d_in[8];
  const float* b_b   = (const float*)d_in[9];
  const float* Wout  = (const float*)d_in[10];
  const float* bout  = (const float*)d_in[11];
  const float* startv= (const float*)d_in[12];
  const float* endv  = (const float*)d_in[13];
  const float* trans = (const float*)d_in[14];
  char* ws = (char*)d_ws;
  // layout (~164 MB): wihg 1MB | whh8 0.5MB | xw 128MB | hout 32MB | em 2.25MB
  unsigned short* wihg = (unsigned short*)(ws);
  unsigned char*  whh8 = (unsigned char*)(ws + (size_t)1048576);
  unsigned char*  xw   = (unsigned char*)(ws + (size_t)1572864);
  unsigned char*  hout = (unsigned char*)(ws + (size_t)135790592);
  float* em            = (float*)(ws + (size_t)169345024);
  float* outp = (float*)d_out;

  hipMemsetAsync(outp, 0, sizeof(float), stream);
  prep_frag_k<<<256, 256, 0, stream>>>(Wih_f, Wih_b, wihg, 2048);
  prep_whh8_k<<<256, 256, 0, stream>>>(Whh_f, Whh_b, whh8);
  xw_gemm_k<<<1024, 256, 0, stream>>>(sent, emb, wihg, lens, xw);
  lstm_k<<<16, 512, 0, stream>>>(xw, whh8, b_f, b_b, lens, hout);
  em_k<<<256, 256, 0, stream>>>(hout, Wout, bout, lens, em);
  crf_k<<<32, 256, 0, stream>>>(em, tags, lens, startv, endv, trans, outp);
}

// Round 4
// 2409.738 us; speedup vs baseline: 1.1454x; 1.1454x over previous
//
#include <hip/hip_runtime.h>
#include <hip/hip_bf16.h>

typedef short v8s __attribute__((ext_vector_type(8)));
typedef float v4f __attribute__((ext_vector_type(4)));
typedef float v2f __attribute__((ext_vector_type(2)));

#define T_ 512

__device__ __forceinline__ unsigned short f2bf(float f){
  unsigned int u = __builtin_bit_cast(unsigned int, f);
  unsigned int r = (u + 0x7fffu + ((u>>16)&1u)) >> 16;
  return (unsigned short)r;
}
// HW fp8 (OCP e4m3fn on gfx950) unpack; word-select must be a literal constant
template<int HI>
__device__ __forceinline__ v2f cvt2(unsigned int wsrc){
  return __builtin_amdgcn_cvt_pk_f32_fp8((int)wsrc, HI);
}
__device__ __forceinline__ float sigm(float x){
  float e = exp2f(-1.442695041f*x);
  return __fdividef(1.f, 1.f + e);
}
__device__ __forceinline__ float tanh_f(float x){
  float e = exp2f(2.885390082f*fabsf(x));
  float r = 1.f - __fdividef(2.f, e + 1.f);
  return copysignf(r, x);
}

// bf16 MFMA B-fragment-major layout for Wih (both dirs stacked: Ntot=2048)
__global__ __launch_bounds__(256) void prep_frag_k(
    const float* __restrict__ Wa, const float* __restrict__ Wb,
    unsigned short* __restrict__ out, int Ntot)
{
  int idx = blockIdx.x*256 + threadIdx.x;
  int lane = idx & 63;
  int t2 = idx >> 6;
  int ntiles = Ntot >> 4;
  int ntile = t2 % ntiles;
  int kt = t2 / ntiles;
  if (kt >= 8) return;
  int n  = ntile*16 + (lane & 15);
  int ks = lane >> 4;
  const float* src = (n < 1024) ? (Wa + (size_t)n*256) : (Wb + (size_t)(n-1024)*256);
  int k0 = kt*32 + ks*8;
  unsigned short* d = out + (size_t)idx*8;
  #pragma unroll
  for (int e=0;e<8;++e) d[e] = f2bf(src[k0+e]);
}

// fp8 MFMA B-fragments for Whh (2 dirs): out[((dir*8+kt)*64+ntile)*64+lane] (8 bytes)
__global__ __launch_bounds__(256) void prep_whh8_k(
    const float* __restrict__ Wf, const float* __restrict__ Wb,
    unsigned char* __restrict__ out)
{
  int idx = blockIdx.x*256 + threadIdx.x;      // 65536 threads
  int lane = idx & 63;
  int t2 = idx >> 6;
  int ntile = t2 & 63;
  int kt = (t2>>6) & 7;
  int dir = t2 >> 9;
  const float* W = dir ? Wb : Wf;
  int n = ntile*16 + (lane&15);
  int k0 = kt*32 + (lane>>4)*8;
  const float* p = W + (size_t)n*256 + k0;
  int w0 = __builtin_amdgcn_cvt_pk_fp8_f32(p[0], p[1], 0, 0);
  w0     = __builtin_amdgcn_cvt_pk_fp8_f32(p[2], p[3], w0, 1);
  int w1 = __builtin_amdgcn_cvt_pk_fp8_f32(p[4], p[5], 0, 0);
  w1     = __builtin_amdgcn_cvt_pk_fp8_f32(p[6], p[7], w1, 1);
  *(uint2*)(out + (size_t)idx*8) = make_uint2((unsigned)w0, (unsigned)w1);
}

// xw = x @ [Wih_f; Wih_b]^T (bf16 MFMA), output fp8 in lane-permuted layout:
// xw[(dir*65536+m)*1024 + wv*128 + lr*8 + (q*2+s)]
__global__ __launch_bounds__(256) void xw_gemm_k(
    const int* __restrict__ sent, const float* __restrict__ emb,
    const unsigned short* __restrict__ wihg, const int* __restrict__ lens,
    unsigned char* __restrict__ xw)
{
  int mt = blockIdx.x;                       // 64 rows each
  if (((mt&7)<<6) >= lens[mt>>3]) return;    // tile fully beyond len
  __shared__ unsigned short A[64][264];
  int tid = threadIdx.x;
  {
    int r = tid>>2, q = tid&3;
    int tok = sent[mt*64 + r];
    const float4* s = (const float4*)(emb + (size_t)tok*256 + q*64);
    unsigned short* drow = &A[r][q*64];
    #pragma unroll
    for (int cc=0; cc<16; ++cc){
      float4 v = s[cc];
      uint2 o;
      o.x = (unsigned)f2bf(v.x) | ((unsigned)f2bf(v.y)<<16);
      o.y = (unsigned)f2bf(v.z) | ((unsigned)f2bf(v.w)<<16);
      *(uint2*)(drow + cc*4) = o;
    }
  }
  __syncthreads();
  int w = tid>>6, lane = tid&63, lr = lane&15, lq = lane>>4;
  #pragma unroll 1
  for (int p=0;p<2;++p){
    int wv = w + p*4;
    #pragma unroll 1
    for (int dn=0;dn<2;++dn){
      v4f acc[8][4];
      #pragma unroll
      for (int e=0;e<8;++e)
        #pragma unroll
        for (int m=0;m<4;++m) acc[e][m] = (v4f){0.f,0.f,0.f,0.f};
      #pragma unroll
      for (int kt=0;kt<8;++kt){
        v8s a0 = *(const v8s*)(&A[ 0+lr][kt*32 + lq*8]);
        v8s a1 = *(const v8s*)(&A[16+lr][kt*32 + lq*8]);
        v8s a2 = *(const v8s*)(&A[32+lr][kt*32 + lq*8]);
        v8s a3 = *(const v8s*)(&A[48+lr][kt*32 + lq*8]);
        #pragma unroll
        for (int e=0;e<8;++e){
          int ntile = dn*64 + (e>>1)*16 + wv*2 + (e&1);
          v8s bfr = *(const v8s*)(wihg + ((size_t)(kt*128 + ntile)*64 + lane)*8);
          acc[e][0] = __builtin_amdgcn_mfma_f32_16x16x32_bf16(a0, bfr, acc[e][0], 0,0,0);
          acc[e][1] = __builtin_amdgcn_mfma_f32_16x16x32_bf16(a1, bfr, acc[e][1], 0,0,0);
          acc[e][2] = __builtin_amdgcn_mfma_f32_16x16x32_bf16(a2, bfr, acc[e][2], 0,0,0);
          acc[e][3] = __builtin_amdgcn_mfma_f32_16x16x32_bf16(a3, bfr, acc[e][3], 0,0,0);
        }
      }
      #pragma unroll
      for (int m=0;m<4;++m){
        #pragma unroll
        for (int j=0;j<4;++j){
          int mr = mt*64 + m*16 + lq*4 + j;
          int w0 = __builtin_amdgcn_cvt_pk_fp8_f32(acc[0][m][j], acc[1][m][j], 0, 0);
          w0     = __builtin_amdgcn_cvt_pk_fp8_f32(acc[2][m][j], acc[3][m][j], w0, 1);
          int w1 = __builtin_amdgcn_cvt_pk_fp8_f32(acc[4][m][j], acc[5][m][j], 0, 0);
          w1     = __builtin_amdgcn_cvt_pk_fp8_f32(acc[6][m][j], acc[7][m][j], w1, 1);
          *(uint2*)(xw + ((size_t)dn*65536 + mr)*1024 + wv*128 + lr*8)
              = make_uint2((unsigned)w0, (unsigned)w1);
        }
      }
    }
  }
}

// Recurrence: 16 blocks x 512 threads; block = (dir, 16 sequences).
// Whh fp8 register-resident; h fp8 double-buffered in LDS; ONE raw barrier/step
// (lgkmcnt only -- global stores/loads never drained in-loop).
__global__ __launch_bounds__(512,2) void lstm_k(
    const unsigned char* __restrict__ xw,
    const unsigned char* __restrict__ whh8,
    const float* __restrict__ bfv, const float* __restrict__ bbv,
    const int* __restrict__ lens,
    unsigned char* __restrict__ hout)
{
  int bid = blockIdx.x, dir = bid>>3, grp = bid&7;
  int tid = threadIdx.x, w = tid>>6, lane = tid&63, lr = lane&15, lq = lane>>4;
  __shared__ unsigned char hbuf[2][16][264];
  __shared__ int tmax_s;
  for (int i=tid*4; i<2*16*264; i+=512*4) *(unsigned int*)(&((unsigned char*)hbuf)[i]) = 0u;
  if (tid==0){
    int mx=0;
    for (int i=0;i<16;++i){ int l = lens[grp*16+i]; mx = l>mx? l:mx; }
    tmax_s = mx;
  }
  long long wreg[64];
  const unsigned char* wb = whh8 + (size_t)dir*262144;
  #pragma unroll
  for (int kt=0;kt<8;++kt){
    #pragma unroll
    for (int nt=0;nt<8;++nt){
      int ntile = (nt>>1)*16 + w*2 + (nt&1);
      wreg[kt*8+nt] = *(const long long*)(wb + ((size_t)(kt*64 + ntile)*64 + lane)*8);
    }
  }
  const float* bb = dir ? bbv : bfv;
  float bias[4][2];
  #pragma unroll
  for (int q=0;q<4;++q){
    bias[q][0] = bb[q*256 + w*32 + lr];
    bias[q][1] = bb[q*256 + w*32 + 16 + lr];
  }
  int len_[4];
  #pragma unroll
  for (int j=0;j<4;++j) len_[j] = lens[grp*16 + lq*4 + j];
  float c[4][2] = {{0.f,0.f},{0.f,0.f},{0.f,0.f},{0.f,0.f}};
  const size_t dbase = (size_t)dir*65536;
  __syncthreads();
  int tmax = tmax_s;
  // prologue: prefetch xw for t=0
  uint2 xv[4];
  #pragma unroll
  for (int j=0;j<4;++j){
    int ln = len_[j];
    int te = dir ? (ln-1) : 0;
    xv[j] = *(const uint2*)(xw + (dbase + (size_t)(grp*16+lq*4+j)*T_ + te)*1024
                            + w*128 + lr*8);
  }
  for (int t=0; t<tmax; ++t){
    int cur = t&1, nxt = cur^1;
    // prefetch next step's xw (consumed next iteration -> full latency hiding)
    uint2 xn[4];
    int tn = (t+1<tmax)? t+1 : t;
    #pragma unroll
    for (int j=0;j<4;++j){
      int ln = len_[j];
      int te = (dir && tn<ln) ? (ln-1-tn) : tn;
      xn[j] = *(const uint2*)(xw + (dbase + (size_t)(grp*16+lq*4+j)*T_ + te)*1024
                              + w*128 + lr*8);
    }
    v4f acc[8];
    #pragma unroll
    for (int nt=0;nt<8;++nt) acc[nt] = (v4f){0.f,0.f,0.f,0.f};
    #pragma unroll
    for (int kt=0;kt<8;++kt){
      long long a = *(const long long*)(&hbuf[cur][lr][kt*32 + lq*8]);
      #pragma unroll
      for (int nt=0;nt<8;++nt)
        acc[nt] = __builtin_amdgcn_mfma_f32_16x16x32_fp8_fp8(a, wreg[kt*8+nt], acc[nt], 0,0,0);
    }
    #pragma unroll
    for (int j=0;j<4;++j){
      int ln = len_[j];
      bool valid = t < ln;
      int bseq = grp*16 + lq*4 + j;
      int pos = (dir && valid) ? (ln-1-t) : t;
      v2f xi = cvt2<0>(xv[j].x);
      v2f xf = cvt2<1>(xv[j].x);
      v2f xg = cvt2<0>(xv[j].y);
      v2f xo = cvt2<1>(xv[j].y);
      float hn[2];
      #pragma unroll
      for (int s=0;s<2;++s){
        float gi = acc[0+s][j] + xi[s] + bias[0][s];
        float gf = acc[2+s][j] + xf[s] + bias[1][s];
        float gg = acc[4+s][j] + xg[s] + bias[2][s];
        float go = acc[6+s][j] + xo[s] + bias[3][s];
        float iv = sigm(gi), fv = sigm(gf), gv = tanh_f(gg), ov = sigm(go);
        float cn = fv*c[j][s] + iv*gv;
        hn[s] = ov*tanh_f(cn);
        if (valid) c[j][s] = cn;
      }
      int hp = __builtin_amdgcn_cvt_pk_fp8_f32(hn[0], hn[1], 0, 0);
      unsigned short hu = valid ? (unsigned short)(hp & 0xffff) : (unsigned short)0;
      if (valid){
        hbuf[nxt][lq*4+j][w*32 + lr]      = (unsigned char)(hp & 0xff);
        hbuf[nxt][lq*4+j][w*32 + 16 + lr] = (unsigned char)((hp>>8) & 0xff);
      }
      *(unsigned short*)(hout + (dbase + (size_t)bseq*T_ + pos)*256 + w*32 + lr*2) = hu;
    }
    #pragma unroll
    for (int j=0;j<4;++j) xv[j] = xn[j];
    asm volatile("s_waitcnt lgkmcnt(0)" ::: "memory");
    __builtin_amdgcn_s_barrier();
    __builtin_amdgcn_sched_barrier(0);
  }
}

// em = [h_f, h_b] @ Wout^T + b_out (only t < len); hout fp8, lane-pair-permuted:
// stored position p = w*32 + r*2 + s  holds column col = w*32 + s*16 + r.
__global__ __launch_bounds__(256) void em_k(
    const unsigned char* __restrict__ hout,
    const float* __restrict__ Wout, const float* __restrict__ bout,
    const int* __restrict__ lens,
    float* __restrict__ em)
{
  __shared__ float Ws[9*512];
  for (int i=threadIdx.x;i<9*512;i+=256){
    int k = i>>9, p = i&511;
    int d = p>>8, pp = p&255;
    int ww = pp>>5, rr = (pp>>1)&15, ss = pp&1;
    int col = ww*32 + ss*16 + rr;
    Ws[i] = Wout[k*512 + d*256 + col];
  }
  __syncthreads();
  int m = blockIdx.x*256 + threadIdx.x;
  int b = m>>9, t = m&511;
  if (t >= lens[b]) return;
  const unsigned char* hf = hout + (size_t)m*256;
  const unsigned char* hb = hout + ((size_t)65536 + m)*256;
  float a[9];
  #pragma unroll
  for (int k=0;k<9;++k) a[k] = bout[k];
  for (int cc=0; cc<256; cc+=16){
    uint4 vf = *(const uint4*)(hf+cc);
    uint4 vb = *(const uint4*)(hb+cc);
    float xf[16], xb[16];
    {
      v2f d0=cvt2<0>(vf.x), d1=cvt2<1>(vf.x), d2=cvt2<0>(vf.y), d3=cvt2<1>(vf.y);
      v2f d4=cvt2<0>(vf.z), d5=cvt2<1>(vf.z), d6=cvt2<0>(vf.w), d7=cvt2<1>(vf.w);
      xf[0]=d0.x; xf[1]=d0.y; xf[2]=d1.x; xf[3]=d1.y;
      xf[4]=d2.x; xf[5]=d2.y; xf[6]=d3.x; xf[7]=d3.y;
      xf[8]=d4.x; xf[9]=d4.y; xf[10]=d5.x; xf[11]=d5.y;
      xf[12]=d6.x; xf[13]=d6.y; xf[14]=d7.x; xf[15]=d7.y;
    }
    {
      v2f d0=cvt2<0>(vb.x), d1=cvt2<1>(vb.x), d2=cvt2<0>(vb.y), d3=cvt2<1>(vb.y);
      v2f d4=cvt2<0>(vb.z), d5=cvt2<1>(vb.z), d6=cvt2<0>(vb.w), d7=cvt2<1>(vb.w);
      xb[0]=d0.x; xb[1]=d0.y; xb[2]=d1.x; xb[3]=d1.y;
      xb[4]=d2.x; xb[5]=d2.y; xb[6]=d3.x; xb[7]=d3.y;
      xb[8]=d4.x; xb[9]=d4.y; xb[10]=d5.x; xb[11]=d5.y;
      xb[12]=d6.x; xb[13]=d6.y; xb[14]=d7.x; xb[15]=d7.y;
    }
    #pragma unroll
    for (int k=0;k<9;++k){
      float s=a[k];
      #pragma unroll
      for (int e=0;e<16;++e) s += xf[e]*Ws[k*512+cc+e] + xb[e]*Ws[k*512+256+cc+e];
      a[k]=s;
    }
  }
  float* d = em + (size_t)m*9;
  #pragma unroll
  for (int k=0;k<9;++k) d[k]=a[k];
}

// CRF: one wave per sequence.
__global__ __launch_bounds__(256) void crf_k(
    const float* __restrict__ em, const int* __restrict__ tags,
    const int* __restrict__ lens, const float* __restrict__ startv,
    const float* __restrict__ endv, const float* __restrict__ trans,
    float* __restrict__ out)
{
  int wid = blockIdx.x*4 + (threadIdx.x>>6);
  int lane = threadIdx.x & 63;
  const float* e = em + (size_t)wid*T_*9;
  const int* tg = tags + (size_t)wid*T_;
  int L = lens[wid];
  float p = 0.f;
  for (int t = 1+lane; t < L; t += 64)
    p += trans[tg[t-1]*9 + tg[t]] + e[(size_t)t*9 + tg[t]];
  if (lane==0) p += startv[tg[0]] + e[tg[0]] + endv[tg[L-1]];
  #pragma unroll
  for (int off=32; off; off>>=1) p += __shfl_xor(p, off, 64);
  float tcol[9];
  #pragma unroll
  for (int i=0;i<9;++i) tcol[i] = (lane<9) ? trans[i*9 + lane] : 0.f;
  float alpha = (lane<9) ? (startv[lane] + e[lane]) : -1e30f;
  for (int t=1; t<L; ++t){
    float vs[9]; float mx = -1e30f;
    #pragma unroll
    for (int i=0;i<9;++i){
      float ai = __shfl(alpha, i, 64);
      vs[i] = ai + tcol[i];
      mx = fmaxf(mx, vs[i]);
    }
    float s = 0.f;
    #pragma unroll
    for (int i=0;i<9;++i) s += __expf(vs[i]-mx);
    float na = mx + __logf(s) + ((lane<9)? e[(size_t)t*9+lane] : 0.f);
    alpha = (lane<9) ? na : -1e30f;
  }
  float v = (lane<9) ? (alpha + endv[lane]) : -1e30f;
  float mx = v;
  #pragma unroll
  for (int off=32; off; off>>=1) mx = fmaxf(mx, __shfl_xor(mx, off, 64));
  float s = __expf(v-mx);
  #pragma unroll
  for (int off=32; off; off>>=1) s += __shfl_xor(s, off, 64);
  float logZ = mx + __logf(s);
  if (lane==0) atomicAdd(out, p - logZ);
}

extern "C" void kernel_launch(void* const* d_in, const int* in_sizes, int n_in,
                              void* d_out, int out_size, void* d_ws, size_t ws_size,
                              hipStream_t stream)
{
  const int*   sent  = (const int*)d_in[0];
  const int*   tags  = (const int*)d_in[1];
  const int*   lens  = (const int*)d_in[2];
  const float* emb   = (const float*)d_in[3];
  const float* Wih_f = (const float*)d_in[4];
  const float* Whh_f = (const float*)d_in[5];
  const float* b_f   = (const float*)d_in[6];
  const float* Wih_b = (const float*)d_in[7];
  const float* Whh_b = (const float*)d_in[8];
  const float* b_b   = (const float*)d_in[9];
  const float* Wout  = (const float*)d_in[10];
  const float* bout  = (const float*)d_in[11];
  const float* startv= (const float*)d_in[12];
  const float* endv  = (const float*)d_in[13];
  const float* trans = (const float*)d_in[14];
  char* ws = (char*)d_ws;
  // layout (~172 MB): wihg 1MB | whh8 0.5MB | xw 128MB | hout 32MB | em 2.25MB
  unsigned short* wihg = (unsigned short*)(ws);
  unsigned char*  whh8 = (unsigned char*)(ws + (size_t)1048576);
  unsigned char*  xw   = (unsigned char*)(ws + (size_t)1572864);
  unsigned char*  hout = (unsigned char*)(ws + (size_t)135790592);
  float* em            = (float*)(ws + (size_t)169345024);
  float* outp = (float*)d_out;

  (void)hipMemsetAsync(outp, 0, sizeof(float), stream);
  prep_frag_k<<<256, 256, 0, stream>>>(Wih_f, Wih_b, wihg, 2048);
  prep_whh8_k<<<256, 256, 0, stream>>>(Whh_f, Whh_b, whh8);
  xw_gemm_k<<<1024, 256, 0, stream>>>(sent, emb, wihg, lens, xw);
  lstm_k<<<16, 512, 0, stream>>>(xw, whh8, b_f, b_b, lens, hout);
  em_k<<<256, 256, 0, stream>>>(hout, Wout, bout, lens, em);
  crf_k<<<32, 256, 0, stream>>>(em, tags, lens, startv, endv, trans, outp);
}

// Round 5
// 1643.345 us; speedup vs baseline: 1.6796x; 1.4664x over previous
//
#include <hip/hip_runtime.h>
#include <hip/hip_bf16.h>

typedef short v8s __attribute__((ext_vector_type(8)));
typedef float v4f __attribute__((ext_vector_type(4)));
typedef float v2f __attribute__((ext_vector_type(2)));

#define T_ 512

__device__ __forceinline__ unsigned short f2bf(float f){
  unsigned int u = __builtin_bit_cast(unsigned int, f);
  unsigned int r = (u + 0x7fffu + ((u>>16)&1u)) >> 16;
  return (unsigned short)r;
}
// HW fp8 (OCP e4m3fn on gfx950) unpack; word-select must be a literal constant
template<int HI>
__device__ __forceinline__ v2f cvt2(unsigned int wsrc){
  return __builtin_amdgcn_cvt_pk_f32_fp8((int)wsrc, HI);
}
// Pade(3,2) tanh, clamped. |err| <~1e-2 everywhere; exactly 1.0 at x=3.
// 1 v_rcp + ~7 FMA-class ops, no division sequence, no exp.
__device__ __forceinline__ float tanh_p(float x){
  float x2 = x*x;
  float num = x*(27.f + x2);
  float r = num * __builtin_amdgcn_rcpf(27.f + 9.f*x2);
  return fminf(fmaxf(r, -1.f), 1.f);
}
__device__ __forceinline__ float sigm_p(float x){
  return 0.5f + 0.5f*tanh_p(0.5f*x);
}

// bf16 MFMA B-fragment-major layout for Wih (both dirs stacked: Ntot=2048)
__global__ __launch_bounds__(256) void prep_frag_k(
    const float* __restrict__ Wa, const float* __restrict__ Wb,
    unsigned short* __restrict__ out, int Ntot)
{
  int idx = blockIdx.x*256 + threadIdx.x;
  int lane = idx & 63;
  int t2 = idx >> 6;
  int ntiles = Ntot >> 4;
  int ntile = t2 % ntiles;
  int kt = t2 / ntiles;
  if (kt >= 8) return;
  int n  = ntile*16 + (lane & 15);
  int ks = lane >> 4;
  const float* src = (n < 1024) ? (Wa + (size_t)n*256) : (Wb + (size_t)(n-1024)*256);
  int k0 = kt*32 + ks*8;
  unsigned short* d = out + (size_t)idx*8;
  #pragma unroll
  for (int e=0;e<8;++e) d[e] = f2bf(src[k0+e]);
}

// fp8 MFMA B-fragments for Whh (2 dirs): out[((dir*8+kt)*64+ntile)*64+lane] (8 bytes)
// k-order permuted to match the packed h layout: physical k position
// p = kt*32 + ks*8 + e  holds logical column pi(p) = kt*32 + (e&1)*16 + ks*4 + (e>>1)
__global__ __launch_bounds__(256) void prep_whh8_k(
    const float* __restrict__ Wf, const float* __restrict__ Wb,
    unsigned char* __restrict__ out)
{
  int idx = blockIdx.x*256 + threadIdx.x;      // 65536 threads
  int lane = idx & 63;
  int t2 = idx >> 6;
  int ntile = t2 & 63;
  int kt = (t2>>6) & 7;
  int dir = t2 >> 9;
  const float* W = dir ? Wb : Wf;
  int n = ntile*16 + (lane&15);
  int ks = lane >> 4;
  const float* row = W + (size_t)n*256;
  float v[8];
  #pragma unroll
  for (int e=0;e<8;++e)
    v[e] = row[kt*32 + (e&1)*16 + ks*4 + (e>>1)];
  int w0 = __builtin_amdgcn_cvt_pk_fp8_f32(v[0], v[1], 0, 0);
  w0     = __builtin_amdgcn_cvt_pk_fp8_f32(v[2], v[3], w0, 1);
  int w1 = __builtin_amdgcn_cvt_pk_fp8_f32(v[4], v[5], 0, 0);
  w1     = __builtin_amdgcn_cvt_pk_fp8_f32(v[6], v[7], w1, 1);
  *(uint2*)(out + (size_t)idx*8) = make_uint2((unsigned)w0, (unsigned)w1);
}

// xw = x @ [Wih_f; Wih_b]^T (bf16 MFMA), output fp8 in lane-permuted layout:
// xw[(dir*65536+m)*1024 + wv*128 + lr*8 + (q*2+s)]
__global__ __launch_bounds__(256) void xw_gemm_k(
    const int* __restrict__ sent, const float* __restrict__ emb,
    const unsigned short* __restrict__ wihg, const int* __restrict__ lens,
    unsigned char* __restrict__ xw)
{
  int mt = blockIdx.x;                       // 64 rows each
  if (((mt&7)<<6) >= lens[mt>>3]) return;    // tile fully beyond len
  __shared__ unsigned short A[64][264];
  int tid = threadIdx.x;
  {
    int r = tid>>2, q = tid&3;
    int tok = sent[mt*64 + r];
    const float4* s = (const float4*)(emb + (size_t)tok*256 + q*64);
    unsigned short* drow = &A[r][q*64];
    #pragma unroll
    for (int cc=0; cc<16; ++cc){
      float4 v = s[cc];
      uint2 o;
      o.x = (unsigned)f2bf(v.x) | ((unsigned)f2bf(v.y)<<16);
      o.y = (unsigned)f2bf(v.z) | ((unsigned)f2bf(v.w)<<16);
      *(uint2*)(drow + cc*4) = o;
    }
  }
  __syncthreads();
  int w = tid>>6, lane = tid&63, lr = lane&15, lq = lane>>4;
  #pragma unroll 1
  for (int p=0;p<2;++p){
    int wv = w + p*4;
    #pragma unroll 1
    for (int dn=0;dn<2;++dn){
      v4f acc[8][4];
      #pragma unroll
      for (int e=0;e<8;++e)
        #pragma unroll
        for (int m=0;m<4;++m) acc[e][m] = (v4f){0.f,0.f,0.f,0.f};
      #pragma unroll
      for (int kt=0;kt<8;++kt){
        v8s a0 = *(const v8s*)(&A[ 0+lr][kt*32 + lq*8]);
        v8s a1 = *(const v8s*)(&A[16+lr][kt*32 + lq*8]);
        v8s a2 = *(const v8s*)(&A[32+lr][kt*32 + lq*8]);
        v8s a3 = *(const v8s*)(&A[48+lr][kt*32 + lq*8]);
        #pragma unroll
        for (int e=0;e<8;++e){
          int ntile = dn*64 + (e>>1)*16 + wv*2 + (e&1);
          v8s bfr = *(const v8s*)(wihg + ((size_t)(kt*128 + ntile)*64 + lane)*8);
          acc[e][0] = __builtin_amdgcn_mfma_f32_16x16x32_bf16(a0, bfr, acc[e][0], 0,0,0);
          acc[e][1] = __builtin_amdgcn_mfma_f32_16x16x32_bf16(a1, bfr, acc[e][1], 0,0,0);
          acc[e][2] = __builtin_amdgcn_mfma_f32_16x16x32_bf16(a2, bfr, acc[e][2], 0,0,0);
          acc[e][3] = __builtin_amdgcn_mfma_f32_16x16x32_bf16(a3, bfr, acc[e][3], 0,0,0);
        }
      }
      #pragma unroll
      for (int m=0;m<4;++m){
        #pragma unroll
        for (int j=0;j<4;++j){
          int mr = mt*64 + m*16 + lq*4 + j;
          int w0 = __builtin_amdgcn_cvt_pk_fp8_f32(acc[0][m][j], acc[1][m][j], 0, 0);
          w0     = __builtin_amdgcn_cvt_pk_fp8_f32(acc[2][m][j], acc[3][m][j], w0, 1);
          int w1 = __builtin_amdgcn_cvt_pk_fp8_f32(acc[4][m][j], acc[5][m][j], 0, 0);
          w1     = __builtin_amdgcn_cvt_pk_fp8_f32(acc[6][m][j], acc[7][m][j], w1, 1);
          *(uint2*)(xw + ((size_t)dn*65536 + mr)*1024 + wv*128 + lr*8)
              = make_uint2((unsigned)w0, (unsigned)w1);
        }
      }
    }
  }
}

// Recurrence: 16 blocks x 512 threads; block = (dir, 16 sequences).
// Whh fp8 register-resident; h fp8 double-buffered in LDS (packed pi-layout);
// ONE raw barrier/step (lgkmcnt only); div/exp-free Pade nonlinearities.
__global__ __launch_bounds__(512,2) void lstm_k(
    const unsigned char* __restrict__ xw,
    const unsigned char* __restrict__ whh8,
    const float* __restrict__ bfv, const float* __restrict__ bbv,
    const int* __restrict__ lens,
    unsigned char* __restrict__ hout)
{
  int bid = blockIdx.x, dir = bid>>3, grp = bid&7;
  int tid = threadIdx.x, w = tid>>6, lane = tid&63, lr = lane&15, lq = lane>>4;
  __shared__ unsigned char hbuf[2][16][264];
  __shared__ int tmax_s;
  for (int i=tid*4; i<2*16*264; i+=512*4) *(unsigned int*)(&((unsigned char*)hbuf)[i]) = 0u;
  if (tid==0){
    int mx=0;
    for (int i=0;i<16;++i){ int l = lens[grp*16+i]; mx = l>mx? l:mx; }
    tmax_s = mx;
  }
  long long wreg[64];
  const unsigned char* wb = whh8 + (size_t)dir*262144;
  #pragma unroll
  for (int kt=0;kt<8;++kt){
    #pragma unroll
    for (int nt=0;nt<8;++nt){
      int ntile = (nt>>1)*16 + w*2 + (nt&1);
      wreg[kt*8+nt] = *(const long long*)(wb + ((size_t)(kt*64 + ntile)*64 + lane)*8);
    }
  }
  const float* bb = dir ? bbv : bfv;
  float bias[4][2];
  #pragma unroll
  for (int q=0;q<4;++q){
    bias[q][0] = bb[q*256 + w*32 + lr];
    bias[q][1] = bb[q*256 + w*32 + 16 + lr];
  }
  int len_[4];
  #pragma unroll
  for (int j=0;j<4;++j) len_[j] = lens[grp*16 + lq*4 + j];
  float c[4][2] = {{0.f,0.f},{0.f,0.f},{0.f,0.f},{0.f,0.f}};
  const size_t dbase = (size_t)dir*65536;
  __syncthreads();
  int tmax = tmax_s;
  // prologue: prefetch xw for t=0
  uint2 xv[4];
  #pragma unroll
  for (int j=0;j<4;++j){
    int ln = len_[j];
    int te = dir ? (ln-1) : 0;
    xv[j] = *(const uint2*)(xw + (dbase + (size_t)(grp*16+lq*4+j)*T_ + te)*1024
                            + w*128 + lr*8);
  }
  for (int t=0; t<tmax; ++t){
    int cur = t&1, nxt = cur^1;
    // prefetch next step's xw (consumed next iteration -> full latency hiding)
    uint2 xn[4];
    int tn = (t+1<tmax)? t+1 : t;
    #pragma unroll
    for (int j=0;j<4;++j){
      int ln = len_[j];
      int te = (dir && tn<ln) ? (ln-1-tn) : tn;
      xn[j] = *(const uint2*)(xw + (dbase + (size_t)(grp*16+lq*4+j)*T_ + te)*1024
                              + w*128 + lr*8);
    }
    v4f acc[8];
    #pragma unroll
    for (int nt=0;nt<8;++nt) acc[nt] = (v4f){0.f,0.f,0.f,0.f};
    #pragma unroll
    for (int kt=0;kt<8;++kt){
      long long a = *(const long long*)(&hbuf[cur][lr][kt*32 + lq*8]);
      #pragma unroll
      for (int nt=0;nt<8;++nt)
        acc[nt] = __builtin_amdgcn_mfma_f32_16x16x32_fp8_fp8(a, wreg[kt*8+nt], acc[nt], 0,0,0);
    }
    #pragma unroll
    for (int j=0;j<4;++j){
      int ln = len_[j];
      bool valid = t < ln;
      int bseq = grp*16 + lq*4 + j;
      int pos = (dir && valid) ? (ln-1-t) : t;
      v2f xi = cvt2<0>(xv[j].x);
      v2f xf = cvt2<1>(xv[j].x);
      v2f xg = cvt2<0>(xv[j].y);
      v2f xo = cvt2<1>(xv[j].y);
      float hn[2];
      #pragma unroll
      for (int s=0;s<2;++s){
        float gi = acc[0+s][j] + xi[s] + bias[0][s];
        float gf = acc[2+s][j] + xf[s] + bias[1][s];
        float gg = acc[4+s][j] + xg[s] + bias[2][s];
        float go = acc[6+s][j] + xo[s] + bias[3][s];
        float iv = sigm_p(gi), fv = sigm_p(gf), gv = tanh_p(gg), ov = sigm_p(go);
        float cn = fv*c[j][s] + iv*gv;
        hn[s] = ov*tanh_p(cn);
        if (valid) c[j][s] = cn;
      }
      int hp = __builtin_amdgcn_cvt_pk_fp8_f32(hn[0], hn[1], 0, 0);
      unsigned short hu = valid ? (unsigned short)(hp & 0xffff) : (unsigned short)0;
      if (valid)
        *(unsigned short*)(&hbuf[nxt][lq*4+j][w*32 + lr*2]) = hu;
      *(unsigned short*)(hout + (dbase + (size_t)bseq*T_ + pos)*256 + w*32 + lr*2) = hu;
    }
    #pragma unroll
    for (int j=0;j<4;++j) xv[j] = xn[j];
    asm volatile("s_waitcnt lgkmcnt(0)" ::: "memory");
    __builtin_amdgcn_s_barrier();
    __builtin_amdgcn_sched_barrier(0);
  }
}

// em = [h_f, h_b] @ Wout^T + b_out (only t < len); hout fp8, lane-pair-permuted:
// stored position p = w*32 + r*2 + s  holds column col = w*32 + s*16 + r.
__global__ __launch_bounds__(256) void em_k(
    const unsigned char* __restrict__ hout,
    const float* __restrict__ Wout, const float* __restrict__ bout,
    const int* __restrict__ lens,
    float* __restrict__ em)
{
  __shared__ float Ws[9*512];
  for (int i=threadIdx.x;i<9*512;i+=256){
    int k = i>>9, p = i&511;
    int d = p>>8, pp = p&255;
    int ww = pp>>5, rr = (pp>>1)&15, ss = pp&1;
    int col = ww*32 + ss*16 + rr;
    Ws[i] = Wout[k*512 + d*256 + col];
  }
  __syncthreads();
  int m = blockIdx.x*256 + threadIdx.x;
  int b = m>>9, t = m&511;
  if (t >= lens[b]) return;
  const unsigned char* hf = hout + (size_t)m*256;
  const unsigned char* hb = hout + ((size_t)65536 + m)*256;
  float a[9];
  #pragma unroll
  for (int k=0;k<9;++k) a[k] = bout[k];
  for (int cc=0; cc<256; cc+=16){
    uint4 vf = *(const uint4*)(hf+cc);
    uint4 vb = *(const uint4*)(hb+cc);
    float xf[16], xb[16];
    {
      v2f d0=cvt2<0>(vf.x), d1=cvt2<1>(vf.x), d2=cvt2<0>(vf.y), d3=cvt2<1>(vf.y);
      v2f d4=cvt2<0>(vf.z), d5=cvt2<1>(vf.z), d6=cvt2<0>(vf.w), d7=cvt2<1>(vf.w);
      xf[0]=d0.x; xf[1]=d0.y; xf[2]=d1.x; xf[3]=d1.y;
      xf[4]=d2.x; xf[5]=d2.y; xf[6]=d3.x; xf[7]=d3.y;
      xf[8]=d4.x; xf[9]=d4.y; xf[10]=d5.x; xf[11]=d5.y;
      xf[12]=d6.x; xf[13]=d6.y; xf[14]=d7.x; xf[15]=d7.y;
    }
    {
      v2f d0=cvt2<0>(vb.x), d1=cvt2<1>(vb.x), d2=cvt2<0>(vb.y), d3=cvt2<1>(vb.y);
      v2f d4=cvt2<0>(vb.z), d5=cvt2<1>(vb.z), d6=cvt2<0>(vb.w), d7=cvt2<1>(vb.w);
      xb[0]=d0.x; xb[1]=d0.y; xb[2]=d1.x; xb[3]=d1.y;
      xb[4]=d2.x; xb[5]=d2.y; xb[6]=d3.x; xb[7]=d3.y;
      xb[8]=d4.x; xb[9]=d4.y; xb[10]=d5.x; xb[11]=d5.y;
      xb[12]=d6.x; xb[13]=d6.y; xb[14]=d7.x; xb[15]=d7.y;
    }
    #pragma unroll
    for (int k=0;k<9;++k){
      float s=a[k];
      #pragma unroll
      for (int e=0;e<16;++e) s += xf[e]*Ws[k*512+cc+e] + xb[e]*Ws[k*512+256+cc+e];
      a[k]=s;
    }
  }
  float* d = em + (size_t)m*9;
  #pragma unroll
  for (int k=0;k<9;++k) d[k]=a[k];
}

// CRF: one wave per sequence.
__global__ __launch_bounds__(256) void crf_k(
    const float* __restrict__ em, const int* __restrict__ tags,
    const int* __restrict__ lens, const float* __restrict__ startv,
    const float* __restrict__ endv, const float* __restrict__ trans,
    float* __restrict__ out)
{
  int wid = blockIdx.x*4 + (threadIdx.x>>6);
  int lane = threadIdx.x & 63;
  const float* e = em + (size_t)wid*T_*9;
  const int* tg = tags + (size_t)wid*T_;
  int L = lens[wid];
  float p = 0.f;
  for (int t = 1+lane; t < L; t += 64)
    p += trans[tg[t-1]*9 + tg[t]] + e[(size_t)t*9 + tg[t]];
  if (lane==0) p += startv[tg[0]] + e[tg[0]] + endv[tg[L-1]];
  #pragma unroll
  for (int off=32; off; off>>=1) p += __shfl_xor(p, off, 64);
  float tcol[9];
  #pragma unroll
  for (int i=0;i<9;++i) tcol[i] = (lane<9) ? trans[i*9 + lane] : 0.f;
  float alpha = (lane<9) ? (startv[lane] + e[lane]) : -1e30f;
  for (int t=1; t<L; ++t){
    float vs[9]; float mx = -1e30f;
    #pragma unroll
    for (int i=0;i<9;++i){
      float ai = __shfl(alpha, i, 64);
      vs[i] = ai + tcol[i];
      mx = fmaxf(mx, vs[i]);
    }
    float s = 0.f;
    #pragma unroll
    for (int i=0;i<9;++i) s += __expf(vs[i]-mx);
    float na = mx + __logf(s) + ((lane<9)? e[(size_t)t*9+lane] : 0.f);
    alpha = (lane<9) ? na : -1e30f;
  }
  float v = (lane<9) ? (alpha + endv[lane]) : -1e30f;
  float mx = v;
  #pragma unroll
  for (int off=32; off; off>>=1) mx = fmaxf(mx, __shfl_xor(mx, off, 64));
  float s = __expf(v-mx);
  #pragma unroll
  for (int off=32; off; off>>=1) s += __shfl_xor(s, off, 64);
  float logZ = mx + __logf(s);
  if (lane==0) atomicAdd(out, p - logZ);
}

extern "C" void kernel_launch(void* const* d_in, const int* in_sizes, int n_in,
                              void* d_out, int out_size, void* d_ws, size_t ws_size,
                              hipStream_t stream)
{
  const int*   sent  = (const int*)d_in[0];
  const int*   tags  = (const int*)d_in[1];
  const int*   lens  = (const int*)d_in[2];
  const float* emb   = (const float*)d_in[3];
  const float* Wih_f = (const float*)d_in[4];
  const float* Whh_f = (const float*)d_in[5];
  const float* b_f   = (const float*)d_in[6];
  const float* Wih_b = (const float*)d_in[7];
  const float* Whh_b = (const float*)d_in[8];
  const float* b_b   = (const float*)d_in[9];
  const float* Wout  = (const float*)d_in[10];
  const float* bout  = (const float*)d_in[11];
  const float* startv= (const float*)d_in[12];
  const float* endv  = (const float*)d_in[13];
  const float* trans = (const float*)d_in[14];
  char* ws = (char*)d_ws;
  // layout (~172 MB): wihg 1MB | whh8 0.5MB | xw 128MB | hout 32MB | em 2.25MB
  unsigned short* wihg = (unsigned short*)(ws);
  unsigned char*  whh8 = (unsigned char*)(ws + (size_t)1048576);
  unsigned char*  xw   = (unsigned char*)(ws + (size_t)1572864);
  unsigned char*  hout = (unsigned char*)(ws + (size_t)135790592);
  float* em            = (float*)(ws + (size_t)169345024);
  float* outp = (float*)d_out;

  (void)hipMemsetAsync(outp, 0, sizeof(float), stream);
  prep_frag_k<<<256, 256, 0, stream>>>(Wih_f, Wih_b, wihg, 2048);
  prep_whh8_k<<<256, 256, 0, stream>>>(Whh_f, Whh_b, whh8);
  xw_gemm_k<<<1024, 256, 0, stream>>>(sent, emb, wihg, lens, xw);
  lstm_k<<<16, 512, 0, stream>>>(xw, whh8, b_f, b_b, lens, hout);
  em_k<<<256, 256, 0, stream>>>(hout, Wout, bout, lens, em);
  crf_k<<<32, 256, 0, stream>>>(em, tags, lens, startv, endv, trans, outp);
}

// Round 6
// 1014.533 us; speedup vs baseline: 2.7206x; 1.6198x over previous
//
#include <hip/hip_runtime.h>
#include <hip/hip_bf16.h>

typedef short v8s __attribute__((ext_vector_type(8)));
typedef float v4f __attribute__((ext_vector_type(4)));
typedef float v2f __attribute__((ext_vector_type(2)));

#define T_ 512

__device__ __forceinline__ unsigned short f2bf(float f){
  unsigned int u = __builtin_bit_cast(unsigned int, f);
  unsigned int r = (u + 0x7fffu + ((u>>16)&1u)) >> 16;
  return (unsigned short)r;
}
// HW fp8 (OCP e4m3fn on gfx950) unpack; word-select must be a literal constant
template<int HI>
__device__ __forceinline__ v2f cvt2(unsigned int wsrc){
  return __builtin_amdgcn_cvt_pk_f32_fp8((int)wsrc, HI);
}
// Pade(3,2) tanh, clamped. |err| <~1e-2 everywhere; exactly 1.0 at x=3.
__device__ __forceinline__ float tanh_p(float x){
  float x2 = x*x;
  float num = x*(27.f + x2);
  float r = num * __builtin_amdgcn_rcpf(27.f + 9.f*x2);
  return fminf(fmaxf(r, -1.f), 1.f);
}
__device__ __forceinline__ float sigm_p(float x){
  return 0.5f + 0.5f*tanh_p(0.5f*x);
}

// bf16 MFMA B-fragment-major layout for Wih (both dirs stacked: Ntot=2048)
__global__ __launch_bounds__(256) void prep_frag_k(
    const float* __restrict__ Wa, const float* __restrict__ Wb,
    unsigned short* __restrict__ out, int Ntot)
{
  int idx = blockIdx.x*256 + threadIdx.x;
  int lane = idx & 63;
  int t2 = idx >> 6;
  int ntiles = Ntot >> 4;
  int ntile = t2 % ntiles;
  int kt = t2 / ntiles;
  if (kt >= 8) return;
  int n  = ntile*16 + (lane & 15);
  int ks = lane >> 4;
  const float* src = (n < 1024) ? (Wa + (size_t)n*256) : (Wb + (size_t)(n-1024)*256);
  int k0 = kt*32 + ks*8;
  unsigned short* d = out + (size_t)idx*8;
  #pragma unroll
  for (int e=0;e<8;++e) d[e] = f2bf(src[k0+e]);
}

// fp8 MFMA B-fragments for Whh (2 dirs): out[((dir*8+kt)*64+ntile)*64+lane] (8 bytes)
// k-order permuted to match the packed h layout: physical k position
// p = kt*32 + ks*8 + e  holds logical column pi(p) = kt*32 + (e&1)*16 + ks*4 + (e>>1)
__global__ __launch_bounds__(256) void prep_whh8_k(
    const float* __restrict__ Wf, const float* __restrict__ Wb,
    unsigned char* __restrict__ out)
{
  int idx = blockIdx.x*256 + threadIdx.x;      // 65536 threads
  int lane = idx & 63;
  int t2 = idx >> 6;
  int ntile = t2 & 63;
  int kt = (t2>>6) & 7;
  int dir = t2 >> 9;
  const float* W = dir ? Wb : Wf;
  int n = ntile*16 + (lane&15);
  int ks = lane >> 4;
  const float* row = W + (size_t)n*256;
  float v[8];
  #pragma unroll
  for (int e=0;e<8;++e)
    v[e] = row[kt*32 + (e&1)*16 + ks*4 + (e>>1)];
  int w0 = __builtin_amdgcn_cvt_pk_fp8_f32(v[0], v[1], 0, 0);
  w0     = __builtin_amdgcn_cvt_pk_fp8_f32(v[2], v[3], w0, 1);
  int w1 = __builtin_amdgcn_cvt_pk_fp8_f32(v[4], v[5], 0, 0);
  w1     = __builtin_amdgcn_cvt_pk_fp8_f32(v[6], v[7], w1, 1);
  *(uint2*)(out + (size_t)idx*8) = make_uint2((unsigned)w0, (unsigned)w1);
}

// xw = x @ [Wih_f; Wih_b]^T (bf16 MFMA), output fp8 in lane-permuted layout:
// xw[(dir*65536+m)*1024 + wv*128 + lr*8 + (q*2+s)]
__global__ __launch_bounds__(256) void xw_gemm_k(
    const int* __restrict__ sent, const float* __restrict__ emb,
    const unsigned short* __restrict__ wihg, const int* __restrict__ lens,
    unsigned char* __restrict__ xw)
{
  int mt = blockIdx.x;                       // 64 rows each
  if (((mt&7)<<6) >= lens[mt>>3]) return;    // tile fully beyond len
  __shared__ unsigned short A[64][264];
  int tid = threadIdx.x;
  {
    int r = tid>>2, q = tid&3;
    int tok = sent[mt*64 + r];
    const float4* s = (const float4*)(emb + (size_t)tok*256 + q*64);
    unsigned short* drow = &A[r][q*64];
    #pragma unroll
    for (int cc=0; cc<16; ++cc){
      float4 v = s[cc];
      uint2 o;
      o.x = (unsigned)f2bf(v.x) | ((unsigned)f2bf(v.y)<<16);
      o.y = (unsigned)f2bf(v.z) | ((unsigned)f2bf(v.w)<<16);
      *(uint2*)(drow + cc*4) = o;
    }
  }
  __syncthreads();
  int w = tid>>6, lane = tid&63, lr = lane&15, lq = lane>>4;
  #pragma unroll 1
  for (int p=0;p<2;++p){
    int wv = w + p*4;
    #pragma unroll 1
    for (int dn=0;dn<2;++dn){
      v4f acc[8][4];
      #pragma unroll
      for (int e=0;e<8;++e)
        #pragma unroll
        for (int m=0;m<4;++m) acc[e][m] = (v4f){0.f,0.f,0.f,0.f};
      #pragma unroll
      for (int kt=0;kt<8;++kt){
        v8s a0 = *(const v8s*)(&A[ 0+lr][kt*32 + lq*8]);
        v8s a1 = *(const v8s*)(&A[16+lr][kt*32 + lq*8]);
        v8s a2 = *(const v8s*)(&A[32+lr][kt*32 + lq*8]);
        v8s a3 = *(const v8s*)(&A[48+lr][kt*32 + lq*8]);
        #pragma unroll
        for (int e=0;e<8;++e){
          int ntile = dn*64 + (e>>1)*16 + wv*2 + (e&1);
          v8s bfr = *(const v8s*)(wihg + ((size_t)(kt*128 + ntile)*64 + lane)*8);
          acc[e][0] = __builtin_amdgcn_mfma_f32_16x16x32_bf16(a0, bfr, acc[e][0], 0,0,0);
          acc[e][1] = __builtin_amdgcn_mfma_f32_16x16x32_bf16(a1, bfr, acc[e][1], 0,0,0);
          acc[e][2] = __builtin_amdgcn_mfma_f32_16x16x32_bf16(a2, bfr, acc[e][2], 0,0,0);
          acc[e][3] = __builtin_amdgcn_mfma_f32_16x16x32_bf16(a3, bfr, acc[e][3], 0,0,0);
        }
      }
      #pragma unroll
      for (int m=0;m<4;++m){
        #pragma unroll
        for (int j=0;j<4;++j){
          int mr = mt*64 + m*16 + lq*4 + j;
          int w0 = __builtin_amdgcn_cvt_pk_fp8_f32(acc[0][m][j], acc[1][m][j], 0, 0);
          w0     = __builtin_amdgcn_cvt_pk_fp8_f32(acc[2][m][j], acc[3][m][j], w0, 1);
          int w1 = __builtin_amdgcn_cvt_pk_fp8_f32(acc[4][m][j], acc[5][m][j], 0, 0);
          w1     = __builtin_amdgcn_cvt_pk_fp8_f32(acc[6][m][j], acc[7][m][j], w1, 1);
          *(uint2*)(xw + ((size_t)dn*65536 + mr)*1024 + wv*128 + lr*8)
              = make_uint2((unsigned)w0, (unsigned)w1);
        }
      }
    }
  }
}

// Recurrence: 64 blocks x 512 threads; block = (dir, 4 sequences).
// Seqs placed at A-rows {0,4,8,12} (seq = lq, reg j=0) so every lane owns
// exactly one seq -> wave epilogue path = 2 cells. Whh fp8 register-resident;
// h fp8 double-buffered in LDS; ONE raw barrier/step (lgkmcnt only).
__global__ __launch_bounds__(512,2) void lstm_k(
    const unsigned char* __restrict__ xw,
    const unsigned char* __restrict__ whh8,
    const float* __restrict__ bfv, const float* __restrict__ bbv,
    const int* __restrict__ lens,
    unsigned char* __restrict__ hout)
{
  int bid = blockIdx.x, dir = bid>>5, grp = bid&31;
  int tid = threadIdx.x, w = tid>>6, lane = tid&63, lr = lane&15, lq = lane>>4;
  __shared__ unsigned char hbuf[2][16][264];
  __shared__ int tmax_s;
  for (int i=tid*4; i<2*16*264; i+=512*4) *(unsigned int*)(&((unsigned char*)hbuf)[i]) = 0u;
  if (tid==0){
    int mx=0;
    for (int i=0;i<4;++i){ int l = lens[grp*4+i]; mx = l>mx? l:mx; }
    tmax_s = mx;
  }
  long long wreg[64];
  const unsigned char* wb = whh8 + (size_t)dir*262144;
  #pragma unroll
  for (int kt=0;kt<8;++kt){
    #pragma unroll
    for (int nt=0;nt<8;++nt){
      int ntile = (nt>>1)*16 + w*2 + (nt&1);
      wreg[kt*8+nt] = *(const long long*)(wb + ((size_t)(kt*64 + ntile)*64 + lane)*8);
    }
  }
  const float* bb = dir ? bbv : bfv;
  float bias[4][2];
  #pragma unroll
  for (int q=0;q<4;++q){
    bias[q][0] = bb[q*256 + w*32 + lr];
    bias[q][1] = bb[q*256 + w*32 + 16 + lr];
  }
  int seq = grp*4 + lq;
  int ln = lens[seq];
  float c0 = 0.f, c1 = 0.f;
  const size_t dbase = (size_t)dir*65536;
  const unsigned char* xbase = xw + (dbase + (size_t)seq*T_)*1024 + w*128 + lr*8;
  unsigned char* hbase = hout + (dbase + (size_t)seq*T_)*256 + w*32 + lr*2;
  __syncthreads();
  int tmax = tmax_s;
  // prologue: prefetch xw for t=0
  uint2 xv = *(const uint2*)(xbase + (size_t)(dir ? (ln-1) : 0)*1024);
  for (int t=0; t<tmax; ++t){
    int cur = t&1, nxt = cur^1;
    // prefetch next step's xw (consumed next iteration)
    int tn = (t+1<tmax)? t+1 : t;
    int te = (dir && tn<ln) ? (ln-1-tn) : tn;
    uint2 xn = *(const uint2*)(xbase + (size_t)te*1024);
    v4f acc[8];
    #pragma unroll
    for (int nt=0;nt<8;++nt) acc[nt] = (v4f){0.f,0.f,0.f,0.f};
    #pragma unroll
    for (int kt=0;kt<8;++kt){
      long long a = *(const long long*)(&hbuf[cur][lr][kt*32 + lq*8]);
      #pragma unroll
      for (int nt=0;nt<8;++nt)
        acc[nt] = __builtin_amdgcn_mfma_f32_16x16x32_fp8_fp8(a, wreg[kt*8+nt], acc[nt], 0,0,0);
    }
    bool valid = t < ln;
    int pos = (dir && valid) ? (ln-1-t) : t;
    v2f xi = cvt2<0>(xv.x);
    v2f xf = cvt2<1>(xv.x);
    v2f xg = cvt2<0>(xv.y);
    v2f xo = cvt2<1>(xv.y);
    float hn0, hn1;
    {
      float gi = acc[0][0] + xi[0] + bias[0][0];
      float gf = acc[2][0] + xf[0] + bias[1][0];
      float gg = acc[4][0] + xg[0] + bias[2][0];
      float go = acc[6][0] + xo[0] + bias[3][0];
      float iv = sigm_p(gi), fv = sigm_p(gf), gv = tanh_p(gg), ov = sigm_p(go);
      float cn = fv*c0 + iv*gv;
      hn0 = ov*tanh_p(cn);
      if (valid) c0 = cn;
    }
    {
      float gi = acc[1][0] + xi[1] + bias[0][1];
      float gf = acc[3][0] + xf[1] + bias[1][1];
      float gg = acc[5][0] + xg[1] + bias[2][1];
      float go = acc[7][0] + xo[1] + bias[3][1];
      float iv = sigm_p(gi), fv = sigm_p(gf), gv = tanh_p(gg), ov = sigm_p(go);
      float cn = fv*c1 + iv*gv;
      hn1 = ov*tanh_p(cn);
      if (valid) c1 = cn;
    }
    int hp = __builtin_amdgcn_cvt_pk_fp8_f32(hn0, hn1, 0, 0);
    unsigned short hu = valid ? (unsigned short)(hp & 0xffff) : (unsigned short)0;
    if (valid)
      *(unsigned short*)(&hbuf[nxt][lq*4][w*32 + lr*2]) = hu;
    *(unsigned short*)(hbase + (size_t)pos*256) = hu;
    xv = xn;
    asm volatile("s_waitcnt lgkmcnt(0)" ::: "memory");
    __builtin_amdgcn_s_barrier();
    __builtin_amdgcn_sched_barrier(0);
  }
}

// em = [h_f, h_b] @ Wout^T + b_out (only t < len); hout fp8, lane-pair-permuted:
// stored position p = w*32 + r*2 + s  holds column col = w*32 + s*16 + r.
__global__ __launch_bounds__(256) void em_k(
    const unsigned char* __restrict__ hout,
    const float* __restrict__ Wout, const float* __restrict__ bout,
    const int* __restrict__ lens,
    float* __restrict__ em)
{
  __shared__ float Ws[9*512];
  for (int i=threadIdx.x;i<9*512;i+=256){
    int k = i>>9, p = i&511;
    int d = p>>8, pp = p&255;
    int ww = pp>>5, rr = (pp>>1)&15, ss = pp&1;
    int col = ww*32 + ss*16 + rr;
    Ws[i] = Wout[k*512 + d*256 + col];
  }
  __syncthreads();
  int m = blockIdx.x*256 + threadIdx.x;
  int b = m>>9, t = m&511;
  if (t >= lens[b]) return;
  const unsigned char* hf = hout + (size_t)m*256;
  const unsigned char* hb = hout + ((size_t)65536 + m)*256;
  float a[9];
  #pragma unroll
  for (int k=0;k<9;++k) a[k] = bout[k];
  for (int cc=0; cc<256; cc+=16){
    uint4 vf = *(const uint4*)(hf+cc);
    uint4 vb = *(const uint4*)(hb+cc);
    float xf[16], xb[16];
    {
      v2f d0=cvt2<0>(vf.x), d1=cvt2<1>(vf.x), d2=cvt2<0>(vf.y), d3=cvt2<1>(vf.y);
      v2f d4=cvt2<0>(vf.z), d5=cvt2<1>(vf.z), d6=cvt2<0>(vf.w), d7=cvt2<1>(vf.w);
      xf[0]=d0.x; xf[1]=d0.y; xf[2]=d1.x; xf[3]=d1.y;
      xf[4]=d2.x; xf[5]=d2.y; xf[6]=d3.x; xf[7]=d3.y;
      xf[8]=d4.x; xf[9]=d4.y; xf[10]=d5.x; xf[11]=d5.y;
      xf[12]=d6.x; xf[13]=d6.y; xf[14]=d7.x; xf[15]=d7.y;
    }
    {
      v2f d0=cvt2<0>(vb.x), d1=cvt2<1>(vb.x), d2=cvt2<0>(vb.y), d3=cvt2<1>(vb.y);
      v2f d4=cvt2<0>(vb.z), d5=cvt2<1>(vb.z), d6=cvt2<0>(vb.w), d7=cvt2<1>(vb.w);
      xb[0]=d0.x; xb[1]=d0.y; xb[2]=d1.x; xb[3]=d1.y;
      xb[4]=d2.x; xb[5]=d2.y; xb[6]=d3.x; xb[7]=d3.y;
      xb[8]=d4.x; xb[9]=d4.y; xb[10]=d5.x; xb[11]=d5.y;
      xb[12]=d6.x; xb[13]=d6.y; xb[14]=d7.x; xb[15]=d7.y;
    }
    #pragma unroll
    for (int k=0;k<9;++k){
      float s=a[k];
      #pragma unroll
      for (int e=0;e<16;++e) s += xf[e]*Ws[k*512+cc+e] + xb[e]*Ws[k*512+256+cc+e];
      a[k]=s;
    }
  }
  float* d = em + (size_t)m*9;
  #pragma unroll
  for (int k=0;k<9;++k) d[k]=a[k];
}

// CRF: one wave per sequence.
__global__ __launch_bounds__(256) void crf_k(
    const float* __restrict__ em, const int* __restrict__ tags,
    const int* __restrict__ lens, const float* __restrict__ startv,
    const float* __restrict__ endv, const float* __restrict__ trans,
    float* __restrict__ out)
{
  int wid = blockIdx.x*4 + (threadIdx.x>>6);
  int lane = threadIdx.x & 63;
  const float* e = em + (size_t)wid*T_*9;
  const int* tg = tags + (size_t)wid*T_;
  int L = lens[wid];
  float p = 0.f;
  for (int t = 1+lane; t < L; t += 64)
    p += trans[tg[t-1]*9 + tg[t]] + e[(size_t)t*9 + tg[t]];
  if (lane==0) p += startv[tg[0]] + e[tg[0]] + endv[tg[L-1]];
  #pragma unroll
  for (int off=32; off; off>>=1) p += __shfl_xor(p, off, 64);
  float tcol[9];
  #pragma unroll
  for (int i=0;i<9;++i) tcol[i] = (lane<9) ? trans[i*9 + lane] : 0.f;
  float alpha = (lane<9) ? (startv[lane] + e[lane]) : -1e30f;
  for (int t=1; t<L; ++t){
    float vs[9]; float mx = -1e30f;
    #pragma unroll
    for (int i=0;i<9;++i){
      float ai = __shfl(alpha, i, 64);
      vs[i] = ai + tcol[i];
      mx = fmaxf(mx, vs[i]);
    }
    float s = 0.f;
    #pragma unroll
    for (int i=0;i<9;++i) s += __expf(vs[i]-mx);
    float na = mx + __logf(s) + ((lane<9)? e[(size_t)t*9+lane] : 0.f);
    alpha = (lane<9) ? na : -1e30f;
  }
  float v = (lane<9) ? (alpha + endv[lane]) : -1e30f;
  float mx = v;
  #pragma unroll
  for (int off=32; off; off>>=1) mx = fmaxf(mx, __shfl_xor(mx, off, 64));
  float s = __expf(v-mx);
  #pragma unroll
  for (int off=32; off; off>>=1) s += __shfl_xor(s, off, 64);
  float logZ = mx + __logf(s);
  if (lane==0) atomicAdd(out, p - logZ);
}

extern "C" void kernel_launch(void* const* d_in, const int* in_sizes, int n_in,
                              void* d_out, int out_size, void* d_ws, size_t ws_size,
                              hipStream_t stream)
{
  const int*   sent  = (const int*)d_in[0];
  const int*   tags  = (const int*)d_in[1];
  const int*   lens  = (const int*)d_in[2];
  const float* emb   = (const float*)d_in[3];
  const float* Wih_f = (const float*)d_in[4];
  const float* Whh_f = (const float*)d_in[5];
  const float* b_f   = (const float*)d_in[6];
  const float* Wih_b = (const float*)d_in[7];
  const float* Whh_b = (const float*)d_in[8];
  const float* b_b   = (const float*)d_in[9];
  const float* Wout  = (const float*)d_in[10];
  const float* bout  = (const float*)d_in[11];
  const float* startv= (const float*)d_in[12];
  const float* endv  = (const float*)d_in[13];
  const float* trans = (const float*)d_in[14];
  char* ws = (char*)d_ws;
  // layout (~172 MB): wihg 1MB | whh8 0.5MB | xw 128MB | hout 32MB | em 2.25MB
  unsigned short* wihg = (unsigned short*)(ws);
  unsigned char*  whh8 = (unsigned char*)(ws + (size_t)1048576);
  unsigned char*  xw   = (unsigned char*)(ws + (size_t)1572864);
  unsigned char*  hout = (unsigned char*)(ws + (size_t)135790592);
  float* em            = (float*)(ws + (size_t)169345024);
  float* outp = (float*)d_out;

  (void)hipMemsetAsync(outp, 0, sizeof(float), stream);
  prep_frag_k<<<256, 256, 0, stream>>>(Wih_f, Wih_b, wihg, 2048);
  prep_whh8_k<<<256, 256, 0, stream>>>(Whh_f, Whh_b, whh8);
  xw_gemm_k<<<1024, 256, 0, stream>>>(sent, emb, wihg, lens, xw);
  lstm_k<<<64, 512, 0, stream>>>(xw, whh8, b_f, b_b, lens, hout);
  em_k<<<256, 256, 0, stream>>>(hout, Wout, bout, lens, em);
  crf_k<<<32, 256, 0, stream>>>(em, tags, lens, startv, endv, trans, outp);
}

// Round 7
// 842.651 us; speedup vs baseline: 3.2755x; 1.2040x over previous
//
#include <hip/hip_runtime.h>
#include <hip/hip_bf16.h>

typedef short v8s __attribute__((ext_vector_type(8)));
typedef int   v8i __attribute__((ext_vector_type(8)));
typedef float v4f __attribute__((ext_vector_type(4)));
typedef float v2f __attribute__((ext_vector_type(2)));

#define T_ 512

__device__ __forceinline__ unsigned short f2bf(float f){
  unsigned int u = __builtin_bit_cast(unsigned int, f);
  unsigned int r = (u + 0x7fffu + ((u>>16)&1u)) >> 16;
  return (unsigned short)r;
}
// HW fp8 (OCP e4m3fn on gfx950) unpack; word-select must be a literal constant
template<int HI>
__device__ __forceinline__ v2f cvt2(unsigned int wsrc){
  return __builtin_amdgcn_cvt_pk_f32_fp8((int)wsrc, HI);
}
// Pade(3,2) tanh, clamped. |err| <~1e-2; no div sequence, no exp.
__device__ __forceinline__ float tanh_p(float x){
  float x2 = x*x;
  float num = x*(27.f + x2);
  float r = num * __builtin_amdgcn_rcpf(27.f + 9.f*x2);
  return fminf(fmaxf(r, -1.f), 1.f);
}
__device__ __forceinline__ float sigm_p(float x){
  return 0.5f + 0.5f*tanh_p(0.5f*x);
}
// pi permutation: physical packed position p (0..255) -> logical h column
__device__ __forceinline__ int pi_col(int p){
  return ((p>>5)<<5) + ((p&1)<<4) + ((p&31)>>1);
}
__device__ __forceinline__ v8i ld32(const void* p){
  uint4 lo = *(const uint4*)p;
  uint4 hi = *(const uint4*)((const char*)p + 16);
  v8i r;
  r[0]=(int)lo.x; r[1]=(int)lo.y; r[2]=(int)lo.z; r[3]=(int)lo.w;
  r[4]=(int)hi.x; r[5]=(int)hi.y; r[6]=(int)hi.z; r[7]=(int)hi.w;
  return r;
}

// bf16 MFMA B-fragment-major layout for Wih (both dirs stacked: Ntot=2048)
__global__ __launch_bounds__(256) void prep_frag_k(
    const float* __restrict__ Wa, const float* __restrict__ Wb,
    unsigned short* __restrict__ out, int Ntot)
{
  int idx = blockIdx.x*256 + threadIdx.x;
  int lane = idx & 63;
  int t2 = idx >> 6;
  int ntiles = Ntot >> 4;
  int ntile = t2 % ntiles;
  int kt = t2 / ntiles;
  if (kt >= 8) return;
  int n  = ntile*16 + (lane & 15);
  int ks = lane >> 4;
  const float* src = (n < 1024) ? (Wa + (size_t)n*256) : (Wb + (size_t)(n-1024)*256);
  int k0 = kt*32 + ks*8;
  unsigned short* d = out + (size_t)idx*8;
  #pragma unroll
  for (int e=0;e<8;++e) d[e] = f2bf(src[k0+e]);
}

// K=128 MX fp8 B-fragments for Whh (2 dirs), 32 B per lane:
// frag f = ((dir*2+kt)*64 + ntile)*64 + lane; byte i of lane =
// Whh[n = ntile*16+(lane&15)][ pi(kt*128 + (lane>>4)*32 + i) ]
__global__ __launch_bounds__(256) void prep_whh8_k(
    const float* __restrict__ Wf, const float* __restrict__ Wb,
    unsigned char* __restrict__ out)
{
  int idx = blockIdx.x*256 + threadIdx.x;      // 16384 threads
  int lane = idx & 63;
  int t2 = idx >> 6;                           // 0..255
  int ntile = t2 & 63;
  int kt = (t2>>6) & 1;
  int dir = t2 >> 7;
  const float* W = dir ? Wb : Wf;
  int n = ntile*16 + (lane&15);
  int kbase = kt*128 + (lane>>4)*32;
  const float* row = W + (size_t)n*256;
  unsigned words[8];
  #pragma unroll
  for (int e=0;e<8;++e){
    float v0 = row[pi_col(kbase + e*4 + 0)];
    float v1 = row[pi_col(kbase + e*4 + 1)];
    float v2 = row[pi_col(kbase + e*4 + 2)];
    float v3 = row[pi_col(kbase + e*4 + 3)];
    int w0 = __builtin_amdgcn_cvt_pk_fp8_f32(v0, v1, 0, 0);
    w0     = __builtin_amdgcn_cvt_pk_fp8_f32(v2, v3, w0, 1);
    words[e] = (unsigned)w0;
  }
  unsigned char* d = out + (size_t)idx*32;
  *(uint4*)(d)      = make_uint4(words[0], words[1], words[2], words[3]);
  *(uint4*)(d + 16) = make_uint4(words[4], words[5], words[6], words[7]);
}

// xw = x @ [Wih_f; Wih_b]^T (bf16 MFMA), output fp8 in lane-permuted layout:
// xw[(dir*65536+m)*1024 + wv*128 + lr*8 + (q*2+s)]
__global__ __launch_bounds__(256) void xw_gemm_k(
    const int* __restrict__ sent, const float* __restrict__ emb,
    const unsigned short* __restrict__ wihg, const int* __restrict__ lens,
    unsigned char* __restrict__ xw)
{
  int mt = blockIdx.x;                       // 64 rows each
  if (((mt&7)<<6) >= lens[mt>>3]) return;    // tile fully beyond len
  __shared__ unsigned short A[64][264];
  int tid = threadIdx.x;
  {
    int r = tid>>2, q = tid&3;
    int tok = sent[mt*64 + r];
    const float4* s = (const float4*)(emb + (size_t)tok*256 + q*64);
    unsigned short* drow = &A[r][q*64];
    #pragma unroll
    for (int cc=0; cc<16; ++cc){
      float4 v = s[cc];
      uint2 o;
      o.x = (unsigned)f2bf(v.x) | ((unsigned)f2bf(v.y)<<16);
      o.y = (unsigned)f2bf(v.z) | ((unsigned)f2bf(v.w)<<16);
      *(uint2*)(drow + cc*4) = o;
    }
  }
  __syncthreads();
  int w = tid>>6, lane = tid&63, lr = lane&15, lq = lane>>4;
  #pragma unroll 1
  for (int p=0;p<2;++p){
    int wv = w + p*4;
    #pragma unroll 1
    for (int dn=0;dn<2;++dn){
      v4f acc[8][4];
      #pragma unroll
      for (int e=0;e<8;++e)
        #pragma unroll
        for (int m=0;m<4;++m) acc[e][m] = (v4f){0.f,0.f,0.f,0.f};
      #pragma unroll
      for (int kt=0;kt<8;++kt){
        v8s a0 = *(const v8s*)(&A[ 0+lr][kt*32 + lq*8]);
        v8s a1 = *(const v8s*)(&A[16+lr][kt*32 + lq*8]);
        v8s a2 = *(const v8s*)(&A[32+lr][kt*32 + lq*8]);
        v8s a3 = *(const v8s*)(&A[48+lr][kt*32 + lq*8]);
        #pragma unroll
        for (int e=0;e<8;++e){
          int ntile = dn*64 + (e>>1)*16 + wv*2 + (e&1);
          v8s bfr = *(const v8s*)(wihg + ((size_t)(kt*128 + ntile)*64 + lane)*8);
          acc[e][0] = __builtin_amdgcn_mfma_f32_16x16x32_bf16(a0, bfr, acc[e][0], 0,0,0);
          acc[e][1] = __builtin_amdgcn_mfma_f32_16x16x32_bf16(a1, bfr, acc[e][1], 0,0,0);
          acc[e][2] = __builtin_amdgcn_mfma_f32_16x16x32_bf16(a2, bfr, acc[e][2], 0,0,0);
          acc[e][3] = __builtin_amdgcn_mfma_f32_16x16x32_bf16(a3, bfr, acc[e][3], 0,0,0);
        }
      }
      #pragma unroll
      for (int m=0;m<4;++m){
        #pragma unroll
        for (int j=0;j<4;++j){
          int mr = mt*64 + m*16 + lq*4 + j;
          int w0 = __builtin_amdgcn_cvt_pk_fp8_f32(acc[0][m][j], acc[1][m][j], 0, 0);
          w0     = __builtin_amdgcn_cvt_pk_fp8_f32(acc[2][m][j], acc[3][m][j], w0, 1);
          int w1 = __builtin_amdgcn_cvt_pk_fp8_f32(acc[4][m][j], acc[5][m][j], 0, 0);
          w1     = __builtin_amdgcn_cvt_pk_fp8_f32(acc[6][m][j], acc[7][m][j], w1, 1);
          *(uint2*)(xw + ((size_t)dn*65536 + mr)*1024 + wv*128 + lr*8)
              = make_uint2((unsigned)w0, (unsigned)w1);
        }
      }
    }
  }
}

// Recurrence: 64 blocks x 512 threads; block = (dir, 4 sequences at A-rows
// {0,4,8,12}). MX-scaled fp8 MFMA (K=128, unit scales) halves matrix-pipe
// time vs 16x16x32. Whh register-resident (128 VGPR); h fp8 in LDS dbuf;
// ONE raw barrier/step (lgkmcnt only).
__global__ __launch_bounds__(512,2) void lstm_k(
    const unsigned char* __restrict__ xw,
    const unsigned char* __restrict__ whh8,
    const float* __restrict__ bfv, const float* __restrict__ bbv,
    const int* __restrict__ lens,
    unsigned char* __restrict__ hout)
{
  int bid = blockIdx.x, dir = bid>>5, grp = bid&31;
  int tid = threadIdx.x, w = tid>>6, lane = tid&63, lr = lane&15, lq = lane>>4;
  __shared__ unsigned char hbuf[2][16][272];   // stride 272: 16B-aligned rows
  __shared__ int tmax_s;
  for (int i=tid*4; i<2*16*272; i+=512*4) *(unsigned int*)(&((unsigned char*)hbuf)[i]) = 0u;
  if (tid==0){
    int mx=0;
    for (int i=0;i<4;++i){ int l = lens[grp*4+i]; mx = l>mx? l:mx; }
    tmax_s = mx;
  }
  // Whh K=128 fragments: wave w owns ntile = q*16 + w*2 + s (q=nt>>1, s=nt&1)
  v8i wreg[16];
  const unsigned char* wb = whh8 + (size_t)dir*262144;
  #pragma unroll
  for (int kt=0;kt<2;++kt){
    #pragma unroll
    for (int nt=0;nt<8;++nt){
      int ntile = (nt>>1)*16 + w*2 + (nt&1);
      wreg[kt*8+nt] = ld32(wb + ((size_t)(kt*64 + ntile)*64 + lane)*32);
    }
  }
  const float* bb = dir ? bbv : bfv;
  float bias[4][2];
  #pragma unroll
  for (int q=0;q<4;++q){
    bias[q][0] = bb[q*256 + w*32 + lr];
    bias[q][1] = bb[q*256 + w*32 + 16 + lr];
  }
  int seq = grp*4 + lq;
  int ln = lens[seq];
  float c0 = 0.f, c1 = 0.f;
  const size_t dbase = (size_t)dir*65536;
  const unsigned char* xbase = xw + (dbase + (size_t)seq*T_)*1024 + w*128 + lr*8;
  unsigned char* hbase = hout + (dbase + (size_t)seq*T_)*256 + w*32 + lr*2;
  __syncthreads();
  int tmax = tmax_s;
  uint2 xv = *(const uint2*)(xbase + (size_t)(dir ? (ln-1) : 0)*1024);
  for (int t=0; t<tmax; ++t){
    int cur = t&1, nxt = cur^1;
    int tn = (t+1<tmax)? t+1 : t;
    int te = (dir && tn<ln) ? (ln-1-tn) : tn;
    uint2 xn = *(const uint2*)(xbase + (size_t)te*1024);
    v4f acc[8];
    #pragma unroll
    for (int nt=0;nt<8;++nt) acc[nt] = (v4f){0.f,0.f,0.f,0.f};
    #pragma unroll
    for (int kt=0;kt<2;++kt){
      v8i a = ld32(&hbuf[cur][lr][kt*128 + lq*32]);
      #pragma unroll
      for (int nt=0;nt<8;++nt)
        acc[nt] = __builtin_amdgcn_mfma_scale_f32_16x16x128_f8f6f4(
                    a, wreg[kt*8+nt], acc[nt],
                    0, 0,                 // cbsz=fp8, blgp=fp8
                    0, 0x7f7f7f7f,        // A scales = 1.0
                    0, 0x7f7f7f7f);       // B scales = 1.0
    }
    bool valid = t < ln;
    int pos = (dir && valid) ? (ln-1-t) : t;
    v2f xi = cvt2<0>(xv.x);
    v2f xf = cvt2<1>(xv.x);
    v2f xg = cvt2<0>(xv.y);
    v2f xo = cvt2<1>(xv.y);
    float hn0, hn1;
    {
      float gi = acc[0][0] + xi[0] + bias[0][0];
      float gf = acc[2][0] + xf[0] + bias[1][0];
      float gg = acc[4][0] + xg[0] + bias[2][0];
      float go = acc[6][0] + xo[0] + bias[3][0];
      float iv = sigm_p(gi), fv = sigm_p(gf), gv = tanh_p(gg), ov = sigm_p(go);
      float cn = fv*c0 + iv*gv;
      hn0 = ov*tanh_p(cn);
      if (valid) c0 = cn;
    }
    {
      float gi = acc[1][0] + xi[1] + bias[0][1];
      float gf = acc[3][0] + xf[1] + bias[1][1];
      float gg = acc[5][0] + xg[1] + bias[2][1];
      float go = acc[7][0] + xo[1] + bias[3][1];
      float iv = sigm_p(gi), fv = sigm_p(gf), gv = tanh_p(gg), ov = sigm_p(go);
      float cn = fv*c1 + iv*gv;
      hn1 = ov*tanh_p(cn);
      if (valid) c1 = cn;
    }
    int hp = __builtin_amdgcn_cvt_pk_fp8_f32(hn0, hn1, 0, 0);
    unsigned short hu = valid ? (unsigned short)(hp & 0xffff) : (unsigned short)0;
    if (valid)
      *(unsigned short*)(&hbuf[nxt][lq*4][w*32 + lr*2]) = hu;
    *(unsigned short*)(hbase + (size_t)pos*256) = hu;
    xv = xn;
    asm volatile("s_waitcnt lgkmcnt(0)" ::: "memory");
    __builtin_amdgcn_s_barrier();
    __builtin_amdgcn_sched_barrier(0);
  }
}

// em = [h_f, h_b] @ Wout^T + b_out. Coalesced: one 16-lane group per 256B row
// (wave covers 4 contiguous rows), 4-stage shfl_xor reduce within group.
__global__ __launch_bounds__(256) void em_k(
    const unsigned char* __restrict__ hout,
    const float* __restrict__ Wout, const float* __restrict__ bout,
    const int* __restrict__ lens,
    float* __restrict__ em)
{
  __shared__ float Ws[9*512];
  for (int i=threadIdx.x;i<9*512;i+=256){
    int k = i>>9, p = i&511;
    int d = p>>8, pp = p&255;
    Ws[i] = Wout[k*512 + d*256 + pi_col(pp)];
  }
  __syncthreads();
  int wv = blockIdx.x*4 + (threadIdx.x>>6);    // wave id, 0..16383
  int lane = threadIdx.x & 63;
  int g = lane>>4, r = lane&15;
  int m = wv*4 + g;                            // row 0..65535
  const unsigned char* hf = hout + (size_t)m*256 + r*16;
  const unsigned char* hb = hout + ((size_t)65536 + m)*256 + r*16;
  uint4 vf = *(const uint4*)hf;
  uint4 vb = *(const uint4*)hb;
  float xf[16], xb[16];
  {
    v2f d0=cvt2<0>(vf.x), d1=cvt2<1>(vf.x), d2=cvt2<0>(vf.y), d3=cvt2<1>(vf.y);
    v2f d4=cvt2<0>(vf.z), d5=cvt2<1>(vf.z), d6=cvt2<0>(vf.w), d7=cvt2<1>(vf.w);
    xf[0]=d0.x; xf[1]=d0.y; xf[2]=d1.x; xf[3]=d1.y;
    xf[4]=d2.x; xf[5]=d2.y; xf[6]=d3.x; xf[7]=d3.y;
    xf[8]=d4.x; xf[9]=d4.y; xf[10]=d5.x; xf[11]=d5.y;
    xf[12]=d6.x; xf[13]=d6.y; xf[14]=d7.x; xf[15]=d7.y;
  }
  {
    v2f d0=cvt2<0>(vb.x), d1=cvt2<1>(vb.x), d2=cvt2<0>(vb.y), d3=cvt2<1>(vb.y);
    v2f d4=cvt2<0>(vb.z), d5=cvt2<1>(vb.z), d6=cvt2<0>(vb.w), d7=cvt2<1>(vb.w);
    xb[0]=d0.x; xb[1]=d0.y; xb[2]=d1.x; xb[3]=d1.y;
    xb[4]=d2.x; xb[5]=d2.y; xb[6]=d3.x; xb[7]=d3.y;
    xb[8]=d4.x; xb[9]=d4.y; xb[10]=d5.x; xb[11]=d5.y;
    xb[12]=d6.x; xb[13]=d6.y; xb[14]=d7.x; xb[15]=d7.y;
  }
  float a[9];
  #pragma unroll
  for (int k=0;k<9;++k){
    float s = 0.f;
    #pragma unroll
    for (int e=0;e<16;++e)
      s += xf[e]*Ws[k*512 + r*16 + e] + xb[e]*Ws[k*512 + 256 + r*16 + e];
    a[k]=s;
  }
  #pragma unroll
  for (int k=0;k<9;++k){
    #pragma unroll
    for (int off=8; off; off>>=1) a[k] += __shfl_xor(a[k], off, 64);
  }
  int b = m>>9, t = m&511;
  if (r==0 && t < lens[b]){
    float* d = em + (size_t)m*9;
    #pragma unroll
    for (int k=0;k<9;++k) d[k] = a[k] + bout[k];
  }
}

// CRF: one wave per sequence.
__global__ __launch_bounds__(256) void crf_k(
    const float* __restrict__ em, const int* __restrict__ tags,
    const int* __restrict__ lens, const float* __restrict__ startv,
    const float* __restrict__ endv, const float* __restrict__ trans,
    float* __restrict__ out)
{
  int wid = blockIdx.x*4 + (threadIdx.x>>6);
  int lane = threadIdx.x & 63;
  const float* e = em + (size_t)wid*T_*9;
  const int* tg = tags + (size_t)wid*T_;
  int L = lens[wid];
  float p = 0.f;
  for (int t = 1+lane; t < L; t += 64)
    p += trans[tg[t-1]*9 + tg[t]] + e[(size_t)t*9 + tg[t]];
  if (lane==0) p += startv[tg[0]] + e[tg[0]] + endv[tg[L-1]];
  #pragma unroll
  for (int off=32; off; off>>=1) p += __shfl_xor(p, off, 64);
  float tcol[9];
  #pragma unroll
  for (int i=0;i<9;++i) tcol[i] = (lane<9) ? trans[i*9 + lane] : 0.f;
  float alpha = (lane<9) ? (startv[lane] + e[lane]) : -1e30f;
  for (int t=1; t<L; ++t){
    float vs[9]; float mx = -1e30f;
    #pragma unroll
    for (int i=0;i<9;++i){
      float ai = __shfl(alpha, i, 64);
      vs[i] = ai + tcol[i];
      mx = fmaxf(mx, vs[i]);
    }
    float s = 0.f;
    #pragma unroll
    for (int i=0;i<9;++i) s += __expf(vs[i]-mx);
    float na = mx + __logf(s) + ((lane<9)? e[(size_t)t*9+lane] : 0.f);
    alpha = (lane<9) ? na : -1e30f;
  }
  float v = (lane<9) ? (alpha + endv[lane]) : -1e30f;
  float mx = v;
  #pragma unroll
  for (int off=32; off; off>>=1) mx = fmaxf(mx, __shfl_xor(mx, off, 64));
  float s = __expf(v-mx);
  #pragma unroll
  for (int off=32; off; off>>=1) s += __shfl_xor(s, off, 64);
  float logZ = mx + __logf(s);
  if (lane==0) atomicAdd(out, p - logZ);
}

extern "C" void kernel_launch(void* const* d_in, const int* in_sizes, int n_in,
                              void* d_out, int out_size, void* d_ws, size_t ws_size,
                              hipStream_t stream)
{
  const int*   sent  = (const int*)d_in[0];
  const int*   tags  = (const int*)d_in[1];
  const int*   lens  = (const int*)d_in[2];
  const float* emb   = (const float*)d_in[3];
  const float* Wih_f = (const float*)d_in[4];
  const float* Whh_f = (const float*)d_in[5];
  const float* b_f   = (const float*)d_in[6];
  const float* Wih_b = (const float*)d_in[7];
  const float* Whh_b = (const float*)d_in[8];
  const float* b_b   = (const float*)d_in[9];
  const float* Wout  = (const float*)d_in[10];
  const float* bout  = (const float*)d_in[11];
  const float* startv= (const float*)d_in[12];
  const float* endv  = (const float*)d_in[13];
  const float* trans = (const float*)d_in[14];
  char* ws = (char*)d_ws;
  // layout (~172 MB): wihg 1MB | whh8 0.5MB | xw 128MB | hout 32MB | em 2.25MB
  unsigned short* wihg = (unsigned short*)(ws);
  unsigned char*  whh8 = (unsigned char*)(ws + (size_t)1048576);
  unsigned char*  xw   = (unsigned char*)(ws + (size_t)1572864);
  unsigned char*  hout = (unsigned char*)(ws + (size_t)135790592);
  float* em            = (float*)(ws + (size_t)169345024);
  float* outp = (float*)d_out;

  (void)hipMemsetAsync(outp, 0, sizeof(float), stream);
  prep_frag_k<<<256, 256, 0, stream>>>(Wih_f, Wih_b, wihg, 2048);
  prep_whh8_k<<<64, 256, 0, stream>>>(Whh_f, Whh_b, whh8);
  xw_gemm_k<<<1024, 256, 0, stream>>>(sent, emb, wihg, lens, xw);
  lstm_k<<<64, 512, 0, stream>>>(xw, whh8, b_f, b_b, lens, hout);
  em_k<<<4096, 256, 0, stream>>>(hout, Wout, bout, lens, em);
  crf_k<<<32, 256, 0, stream>>>(em, tags, lens, startv, endv, trans, outp);
}

// Round 8
// 744.227 us; speedup vs baseline: 3.7087x; 1.1323x over previous
//
#include <hip/hip_runtime.h>
#include <hip/hip_bf16.h>

typedef short v8s __attribute__((ext_vector_type(8)));
typedef int   v8i __attribute__((ext_vector_type(8)));
typedef int   v4i __attribute__((ext_vector_type(4)));
typedef float v4f __attribute__((ext_vector_type(4)));
typedef float v2f __attribute__((ext_vector_type(2)));

#define T_ 512

// HW fp8 (OCP e4m3fn) unpack; word-select must be a literal constant
template<int HI>
__device__ __forceinline__ v2f cvt2(unsigned int wsrc){
  return __builtin_amdgcn_cvt_pk_f32_fp8((int)wsrc, HI);
}
// Pade(3,2) tanh, clamped. |err| <~1e-2; no div sequence, no exp.
__device__ __forceinline__ float tanh_p(float x){
  float x2 = x*x;
  float num = x*(27.f + x2);
  float r = num * __builtin_amdgcn_rcpf(27.f + 9.f*x2);
  return fminf(fmaxf(r, -1.f), 1.f);
}
__device__ __forceinline__ float sigm_p(float x){
  return 0.5f + 0.5f*tanh_p(0.5f*x);
}
// pi permutation: physical packed position p (0..255) -> logical h column
__device__ __forceinline__ int pi_col(int p){
  return ((p>>5)<<5) + ((p&1)<<4) + ((p&31)>>1);
}
__device__ __forceinline__ v8i ld32(const void* p){
  uint4 lo = *(const uint4*)p;
  uint4 hi = *(const uint4*)((const char*)p + 16);
  v8i r;
  r[0]=(int)lo.x; r[1]=(int)lo.y; r[2]=(int)lo.z; r[3]=(int)lo.w;
  r[4]=(int)hi.x; r[5]=(int)hi.y; r[6]=(int)hi.z; r[7]=(int)hi.w;
  return r;
}
// fp4 e2m1 encode of x (magnitudes {0,.5,1,1.5,2,3,4,6})
__device__ __forceinline__ unsigned f2fp4(float x){
  unsigned s = (x < 0.f) ? 8u : 0u;
  float a = fabsf(x);
  unsigned m;
  if      (a < 0.25f) m=0u; else if (a < 0.75f) m=1u;
  else if (a < 1.25f) m=2u; else if (a < 1.75f) m=3u;
  else if (a < 2.5f ) m=4u; else if (a < 3.5f ) m=5u;
  else if (a < 5.f  ) m=6u; else m=7u;
  return s|m;
}
// f32x4 -> packed fp8 dword
__device__ __forceinline__ unsigned pk8(float a, float b, float c, float d){
  int w = __builtin_amdgcn_cvt_pk_fp8_f32(a, b, 0, 0);
  w     = __builtin_amdgcn_cvt_pk_fp8_f32(c, d, w, 1);
  return (unsigned)w;
}

// fp8 K=128 B-fragments for Wih (both dirs, 2048 gate cols):
// frag (kt*128+ntile): byte i of lane = W[n=ntile*16+(lane&15)][kt*128+(lane>>4)*32+i]
__global__ __launch_bounds__(256) void prep_wih8_k(
    const float* __restrict__ Wa, const float* __restrict__ Wb,
    unsigned char* __restrict__ out)
{
  int idx = blockIdx.x*256 + threadIdx.x;      // 16384 threads
  int lane = idx & 63;
  int t2 = idx >> 6;                           // 0..255
  int ntile = t2 & 127;
  int kt = t2 >> 7;
  int n = ntile*16 + (lane&15);
  const float* W = (n < 1024) ? (Wa + (size_t)n*256) : (Wb + (size_t)(n-1024)*256);
  int k0 = kt*128 + (lane>>4)*32;
  unsigned words[8];
  #pragma unroll
  for (int e=0;e<8;++e)
    words[e] = pk8(W[k0+e*4], W[k0+e*4+1], W[k0+e*4+2], W[k0+e*4+3]);
  unsigned char* d = out + (size_t)idx*32;
  *(uint4*)(d)      = make_uint4(words[0], words[1], words[2], words[3]);
  *(uint4*)(d + 16) = make_uint4(words[4], words[5], words[6], words[7]);
}

// fp4 K=128 B-fragments for Whh (2 dirs), 16 B per lane, weights pre-scaled x64,
// k-order pi-permuted to match packed h layout.
__global__ __launch_bounds__(256) void prep_whh4_k(
    const float* __restrict__ Wf, const float* __restrict__ Wb,
    unsigned char* __restrict__ out)
{
  int idx = blockIdx.x*256 + threadIdx.x;      // 16384 threads
  int lane = idx & 63;
  int t2 = idx >> 6;                           // 0..255
  int ntile = t2 & 63;
  int kt = (t2>>6) & 1;
  int dir = t2 >> 7;
  const float* W = dir ? Wb : Wf;
  int n = ntile*16 + (lane&15);
  int kbase = kt*128 + (lane>>4)*32;
  const float* row = W + (size_t)n*256;
  unsigned words[4];
  #pragma unroll
  for (int d4=0;d4<4;++d4){
    unsigned acc = 0;
    #pragma unroll
    for (int j=0;j<8;++j){
      float v = row[pi_col(kbase + d4*8 + j)] * 64.f;
      acc |= f2fp4(v) << (4*j);
    }
    words[d4] = acc;
  }
  *(uint4*)(out + (size_t)idx*16) = make_uint4(words[0], words[1], words[2], words[3]);
}

// xw = x @ [Wih_f; Wih_b]^T + bias (fp8 MX MFMA, K=128), M=128 rows/block.
// Output fp8 lane-permuted: xw[(dn*65536+m)*1024 + v*128 + lr*8 + (q*2+s)]
// holding gate col dn*1024 + q*256 + v*32 + s*16 + lr.
__global__ __launch_bounds__(256) void xw_gemm_k(
    const int* __restrict__ sent, const float* __restrict__ emb,
    const unsigned char* __restrict__ wihg, const int* __restrict__ lens,
    const float* __restrict__ bfv, const float* __restrict__ bbv,
    unsigned char* __restrict__ xw)
{
  int mt = blockIdx.x;                         // 0..511, 128 rows each
  if (((mt&3)<<7) >= lens[mt>>2]) return;      // tile fully beyond len
  __shared__ unsigned char A[128][272];        // fp8 x rows
  int tid = threadIdx.x;
  {
    int row = tid>>1, half = tid&1;
    int tok = sent[mt*128 + row];
    const float4* s = (const float4*)(emb + (size_t)tok*256 + half*128);
    unsigned char* drow = &A[row][half*128];
    #pragma unroll
    for (int c4=0; c4<8; ++c4){
      unsigned w0[4];
      #pragma unroll
      for (int u=0; u<4; ++u){
        float4 v = s[c4*4+u];
        w0[u] = pk8(v.x, v.y, v.z, v.w);
      }
      *(uint4*)(drow + c4*16) = make_uint4(w0[0], w0[1], w0[2], w0[3]);
    }
  }
  __syncthreads();
  int w = tid>>6, lane = tid&63, lr = lane&15, lq = lane>>4;
  #pragma unroll 1
  for (int i4=0; i4<4; ++i4){
    int dnv = w*4 + i4;
    int dn = dnv>>3, v = dnv&7;
    const float* bb = dn ? bbv : bfv;
    float bias[8];
    #pragma unroll
    for (int e=0;e<8;++e){
      int q = e>>1, s = e&1;
      bias[e] = bb[q*256 + v*32 + s*16 + lr];
    }
    #pragma unroll 1
    for (int mh=0; mh<2; ++mh){
      v4f acc[8][4];
      #pragma unroll
      for (int e=0;e<8;++e)
        #pragma unroll
        for (int mm=0;mm<4;++mm) acc[e][mm] = (v4f){0.f,0.f,0.f,0.f};
      #pragma unroll
      for (int kt=0;kt<2;++kt){
        v8i a0 = ld32(&A[mh*64 +  0 + lr][kt*128 + lq*32]);
        v8i a1 = ld32(&A[mh*64 + 16 + lr][kt*128 + lq*32]);
        v8i a2 = ld32(&A[mh*64 + 32 + lr][kt*128 + lq*32]);
        v8i a3 = ld32(&A[mh*64 + 48 + lr][kt*128 + lq*32]);
        #pragma unroll
        for (int e=0;e<8;++e){
          int q = e>>1, s = e&1;
          int ntile = dn*64 + q*16 + v*2 + s;
          v8i bfr = ld32(wihg + ((size_t)(kt*128 + ntile)*64 + lane)*32);
          acc[e][0] = __builtin_amdgcn_mfma_scale_f32_16x16x128_f8f6f4(
                        a0, bfr, acc[e][0], 0,0, 0,0x7f7f7f7f, 0,0x7f7f7f7f);
          acc[e][1] = __builtin_amdgcn_mfma_scale_f32_16x16x128_f8f6f4(
                        a1, bfr, acc[e][1], 0,0, 0,0x7f7f7f7f, 0,0x7f7f7f7f);
          acc[e][2] = __builtin_amdgcn_mfma_scale_f32_16x16x128_f8f6f4(
                        a2, bfr, acc[e][2], 0,0, 0,0x7f7f7f7f, 0,0x7f7f7f7f);
          acc[e][3] = __builtin_amdgcn_mfma_scale_f32_16x16x128_f8f6f4(
                        a3, bfr, acc[e][3], 0,0, 0,0x7f7f7f7f, 0,0x7f7f7f7f);
        }
      }
      #pragma unroll
      for (int mm=0;mm<4;++mm){
        #pragma unroll
        for (int j=0;j<4;++j){
          int row = mt*128 + mh*64 + mm*16 + lq*4 + j;
          unsigned lo = pk8(acc[0][mm][j]+bias[0], acc[1][mm][j]+bias[1],
                            acc[2][mm][j]+bias[2], acc[3][mm][j]+bias[3]);
          unsigned hi = pk8(acc[4][mm][j]+bias[4], acc[5][mm][j]+bias[5],
                            acc[6][mm][j]+bias[6], acc[7][mm][j]+bias[7]);
          *(uint2*)(xw + ((size_t)dn*65536 + row)*1024 + v*128 + lr*8)
              = make_uint2(lo, hi);
        }
      }
    }
  }
}

// Recurrence: 64 blocks x 512 threads; block = (dir, 4 seqs at A-rows {0,4,8,12}).
// Whh fp4 register-resident (64 VGPR), h fp8 in LDS dbuf; MX MFMA A=fp8,B=fp4;
// bias pre-folded into xw; ONE raw barrier/step (lgkmcnt only).
__global__ __launch_bounds__(512,2) void lstm_k(
    const unsigned char* __restrict__ xw,
    const unsigned char* __restrict__ whh4,
    const int* __restrict__ lens,
    unsigned char* __restrict__ hout)
{
  int bid = blockIdx.x, dir = bid>>5, grp = bid&31;
  int tid = threadIdx.x, w = tid>>6, lane = tid&63, lr = lane&15, lq = lane>>4;
  __shared__ unsigned char hbuf[2][16][272];
  __shared__ int tmax_s;
  for (int i=tid*4; i<2*16*272; i+=512*4) *(unsigned int*)(&((unsigned char*)hbuf)[i]) = 0u;
  if (tid==0){
    int mx=0;
    for (int i=0;i<4;++i){ int l = lens[grp*4+i]; mx = l>mx? l:mx; }
    tmax_s = mx;
  }
  // Whh fp4 fragments: wave w owns ntile = q*16 + w*2 + s
  v4i wreg[16];
  const unsigned char* wb = whh4 + (size_t)dir*131072;
  #pragma unroll
  for (int kt=0;kt<2;++kt){
    #pragma unroll
    for (int nt=0;nt<8;++nt){
      int ntile = (nt>>1)*16 + w*2 + (nt&1);
      uint4 t = *(const uint4*)(wb + ((size_t)(kt*64 + ntile)*64 + lane)*16);
      v4i r; r[0]=(int)t.x; r[1]=(int)t.y; r[2]=(int)t.z; r[3]=(int)t.w;
      wreg[kt*8+nt] = r;
    }
  }
  int seq = grp*4 + lq;
  int ln = lens[seq];
  float c0 = 0.f, c1 = 0.f;
  const size_t dbase = (size_t)dir*65536;
  const unsigned char* xbase = xw + (dbase + (size_t)seq*T_)*1024 + w*128 + lr*8;
  unsigned char* hbase = hout + (dbase + (size_t)seq*T_)*256 + w*32 + lr*2;
  __syncthreads();
  int tmax = tmax_s;
  uint2 xv = *(const uint2*)(xbase + (size_t)(dir ? (ln-1) : 0)*1024);
  for (int t=0; t<tmax; ++t){
    int cur = t&1, nxt = cur^1;
    int tn = (t+1<tmax)? t+1 : t;
    int te = (dir && tn<ln) ? (ln-1-tn) : tn;
    uint2 xn = *(const uint2*)(xbase + (size_t)te*1024);
    v4f acc[8];
    #pragma unroll
    for (int nt=0;nt<8;++nt) acc[nt] = (v4f){0.f,0.f,0.f,0.f};
    #pragma unroll
    for (int kt=0;kt<2;++kt){
      v8i a = ld32(&hbuf[cur][lr][kt*128 + lq*32]);
      #pragma unroll
      for (int nt=0;nt<8;++nt){
        v4i wv4 = wreg[kt*8+nt];
        v8i b; b[0]=wv4[0]; b[1]=wv4[1]; b[2]=wv4[2]; b[3]=wv4[3];
        b[4]=0; b[5]=0; b[6]=0; b[7]=0;
        acc[nt] = __builtin_amdgcn_mfma_scale_f32_16x16x128_f8f6f4(
                    a, b, acc[nt],
                    0, 4,                 // cbsz=fp8(A), blgp=fp4(B)
                    0, 0x7f7f7f7f,        // A scales = 1.0
                    0, 0x79797979);       // B scales = 2^-6
      }
    }
    bool valid = t < ln;
    int pos = (dir && valid) ? (ln-1-t) : t;
    v2f xi = cvt2<0>(xv.x);
    v2f xf = cvt2<1>(xv.x);
    v2f xg = cvt2<0>(xv.y);
    v2f xo = cvt2<1>(xv.y);
    float hn0, hn1;
    {
      float gi = acc[0][0] + xi[0];
      float gf = acc[2][0] + xf[0];
      float gg = acc[4][0] + xg[0];
      float go = acc[6][0] + xo[0];
      float iv = sigm_p(gi), fv = sigm_p(gf), gv = tanh_p(gg), ov = sigm_p(go);
      float cn = fv*c0 + iv*gv;
      hn0 = ov*tanh_p(cn);
      if (valid) c0 = cn;
    }
    {
      float gi = acc[1][0] + xi[1];
      float gf = acc[3][0] + xf[1];
      float gg = acc[5][0] + xg[1];
      float go = acc[7][0] + xo[1];
      float iv = sigm_p(gi), fv = sigm_p(gf), gv = tanh_p(gg), ov = sigm_p(go);
      float cn = fv*c1 + iv*gv;
      hn1 = ov*tanh_p(cn);
      if (valid) c1 = cn;
    }
    int hp = __builtin_amdgcn_cvt_pk_fp8_f32(hn0, hn1, 0, 0);
    unsigned short hu = valid ? (unsigned short)(hp & 0xffff) : (unsigned short)0;
    if (valid)
      *(unsigned short*)(&hbuf[nxt][lq*4][w*32 + lr*2]) = hu;
    *(unsigned short*)(hbase + (size_t)pos*256) = hu;
    xv = xn;
    asm volatile("s_waitcnt lgkmcnt(0)" ::: "memory");
    __builtin_amdgcn_s_barrier();
    __builtin_amdgcn_sched_barrier(0);
  }
}

// em = [h_f, h_b] @ Wout^T + b_out. Coalesced: 16-lane group per 256B row.
__global__ __launch_bounds__(256) void em_k(
    const unsigned char* __restrict__ hout,
    const float* __restrict__ Wout, const float* __restrict__ bout,
    const int* __restrict__ lens,
    float* __restrict__ em)
{
  __shared__ float Ws[9*512];
  for (int i=threadIdx.x;i<9*512;i+=256){
    int k = i>>9, p = i&511;
    int d = p>>8, pp = p&255;
    Ws[i] = Wout[k*512 + d*256 + pi_col(pp)];
  }
  __syncthreads();
  int wv = blockIdx.x*4 + (threadIdx.x>>6);
  int lane = threadIdx.x & 63;
  int g = lane>>4, r = lane&15;
  int m = wv*4 + g;
  const unsigned char* hf = hout + (size_t)m*256 + r*16;
  const unsigned char* hb = hout + ((size_t)65536 + m)*256 + r*16;
  uint4 vf = *(const uint4*)hf;
  uint4 vb = *(const uint4*)hb;
  float xf[16], xb[16];
  {
    v2f d0=cvt2<0>(vf.x), d1=cvt2<1>(vf.x), d2=cvt2<0>(vf.y), d3=cvt2<1>(vf.y);
    v2f d4=cvt2<0>(vf.z), d5=cvt2<1>(vf.z), d6=cvt2<0>(vf.w), d7=cvt2<1>(vf.w);
    xf[0]=d0.x; xf[1]=d0.y; xf[2]=d1.x; xf[3]=d1.y;
    xf[4]=d2.x; xf[5]=d2.y; xf[6]=d3.x; xf[7]=d3.y;
    xf[8]=d4.x; xf[9]=d4.y; xf[10]=d5.x; xf[11]=d5.y;
    xf[12]=d6.x; xf[13]=d6.y; xf[14]=d7.x; xf[15]=d7.y;
  }
  {
    v2f d0=cvt2<0>(vb.x), d1=cvt2<1>(vb.x), d2=cvt2<0>(vb.y), d3=cvt2<1>(vb.y);
    v2f d4=cvt2<0>(vb.z), d5=cvt2<1>(vb.z), d6=cvt2<0>(vb.w), d7=cvt2<1>(vb.w);
    xb[0]=d0.x; xb[1]=d0.y; xb[2]=d1.x; xb[3]=d1.y;
    xb[4]=d2.x; xb[5]=d2.y; xb[6]=d3.x; xb[7]=d3.y;
    xb[8]=d4.x; xb[9]=d4.y; xb[10]=d5.x; xb[11]=d5.y;
    xb[12]=d6.x; xb[13]=d6.y; xb[14]=d7.x; xb[15]=d7.y;
  }
  float a[9];
  #pragma unroll
  for (int k=0;k<9;++k){
    float s = 0.f;
    #pragma unroll
    for (int e=0;e<16;++e)
      s += xf[e]*Ws[k*512 + r*16 + e] + xb[e]*Ws[k*512 + 256 + r*16 + e];
    a[k]=s;
  }
  #pragma unroll
  for (int k=0;k<9;++k){
    #pragma unroll
    for (int off=8; off; off>>=1) a[k] += __shfl_xor(a[k], off, 64);
  }
  int b = m>>9, t = m&511;
  if (r==0 && t < lens[b]){
    float* d = em + (size_t)m*9;
    #pragma unroll
    for (int k=0;k<9;++k) d[k] = a[k] + bout[k];
  }
}

// CRF: one wave per sequence.
__global__ __launch_bounds__(256) void crf_k(
    const float* __restrict__ em, const int* __restrict__ tags,
    const int* __restrict__ lens, const float* __restrict__ startv,
    const float* __restrict__ endv, const float* __restrict__ trans,
    float* __restrict__ out)
{
  int wid = blockIdx.x*4 + (threadIdx.x>>6);
  int lane = threadIdx.x & 63;
  const float* e = em + (size_t)wid*T_*9;
  const int* tg = tags + (size_t)wid*T_;
  int L = lens[wid];
  float p = 0.f;
  for (int t = 1+lane; t < L; t += 64)
    p += trans[tg[t-1]*9 + tg[t]] + e[(size_t)t*9 + tg[t]];
  if (lane==0) p += startv[tg[0]] + e[tg[0]] + endv[tg[L-1]];
  #pragma unroll
  for (int off=32; off; off>>=1) p += __shfl_xor(p, off, 64);
  float tcol[9];
  #pragma unroll
  for (int i=0;i<9;++i) tcol[i] = (lane<9) ? trans[i*9 + lane] : 0.f;
  float alpha = (lane<9) ? (startv[lane] + e[lane]) : -1e30f;
  for (int t=1; t<L; ++t){
    float vs[9]; float mx = -1e30f;
    #pragma unroll
    for (int i=0;i<9;++i){
      float ai = __shfl(alpha, i, 64);
      vs[i] = ai + tcol[i];
      mx = fmaxf(mx, vs[i]);
    }
    float s = 0.f;
    #pragma unroll
    for (int i=0;i<9;++i) s += __expf(vs[i]-mx);
    float na = mx + __logf(s) + ((lane<9)? e[(size_t)t*9+lane] : 0.f);
    alpha = (lane<9) ? na : -1e30f;
  }
  float v = (lane<9) ? (alpha + endv[lane]) : -1e30f;
  float mx = v;
  #pragma unroll
  for (int off=32; off; off>>=1) mx = fmaxf(mx, __shfl_xor(mx, off, 64));
  float s = __expf(v-mx);
  #pragma unroll
  for (int off=32; off; off>>=1) s += __shfl_xor(s, off, 64);
  float logZ = mx + __logf(s);
  if (lane==0) atomicAdd(out, p - logZ);
}

extern "C" void kernel_launch(void* const* d_in, const int* in_sizes, int n_in,
                              void* d_out, int out_size, void* d_ws, size_t ws_size,
                              hipStream_t stream)
{
  const int*   sent  = (const int*)d_in[0];
  const int*   tags  = (const int*)d_in[1];
  const int*   lens  = (const int*)d_in[2];
  const float* emb   = (const float*)d_in[3];
  const float* Wih_f = (const float*)d_in[4];
  const float* Whh_f = (const float*)d_in[5];
  const float* b_f   = (const float*)d_in[6];
  const float* Wih_b = (const float*)d_in[7];
  const float* Whh_b = (const float*)d_in[8];
  const float* b_b   = (const float*)d_in[9];
  const float* Wout  = (const float*)d_in[10];
  const float* bout  = (const float*)d_in[11];
  const float* startv= (const float*)d_in[12];
  const float* endv  = (const float*)d_in[13];
  const float* trans = (const float*)d_in[14];
  char* ws = (char*)d_ws;
  // layout (~171 MB): wihg8 0.5MB | whh4 0.25MB | xw 128MB | hout 32MB | em 2.25MB
  unsigned char* wihg8 = (unsigned char*)(ws);
  unsigned char* whh4  = (unsigned char*)(ws + (size_t)524288);
  unsigned char* xw    = (unsigned char*)(ws + (size_t)1048576);
  unsigned char* hout  = (unsigned char*)(ws + (size_t)135266304);
  float* em            = (float*)(ws + (size_t)168820736);
  float* outp = (float*)d_out;

  (void)hipMemsetAsync(outp, 0, sizeof(float), stream);
  prep_wih8_k<<<64, 256, 0, stream>>>(Wih_f, Wih_b, wihg8);
  prep_whh4_k<<<64, 256, 0, stream>>>(Whh_f, Whh_b, whh4);
  xw_gemm_k<<<512, 256, 0, stream>>>(sent, emb, wihg8, lens, b_f, b_b, xw);
  lstm_k<<<64, 512, 0, stream>>>(xw, whh4, lens, hout);
  em_k<<<4096, 256, 0, stream>>>(hout, Wout, bout, lens, em);
  crf_k<<<32, 256, 0, stream>>>(em, tags, lens, startv, endv, trans, outp);
}

// Round 9
// 706.412 us; speedup vs baseline: 3.9072x; 1.0535x over previous
//
#include <hip/hip_runtime.h>
#include <hip/hip_bf16.h>

typedef short v8s __attribute__((ext_vector_type(8)));
typedef int   v8i __attribute__((ext_vector_type(8)));
typedef int   v4i __attribute__((ext_vector_type(4)));
typedef float v4f __attribute__((ext_vector_type(4)));
typedef float v2f __attribute__((ext_vector_type(2)));

#define T_ 512

// HW fp8 (OCP e4m3fn) unpack; word-select must be a literal constant
template<int HI>
__device__ __forceinline__ v2f cvt2(unsigned int wsrc){
  return __builtin_amdgcn_cvt_pk_f32_fp8((int)wsrc, HI);
}
__device__ __forceinline__ v2f rcp2(v2f d){
  return (v2f){__builtin_amdgcn_rcpf(d.x), __builtin_amdgcn_rcpf(d.y)};
}
// packed Pade(3,2) tanh with med3 clamp (2 cells per call)
__device__ __forceinline__ v2f tanh2(v2f x){
  v2f x2 = x*x;
  v2f num = x*(x2 + 27.f);
  v2f den = x2*9.f + 27.f;
  v2f r = num * rcp2(den);
  return (v2f){__builtin_amdgcn_fmed3f(r.x,-1.f,1.f),
               __builtin_amdgcn_fmed3f(r.y,-1.f,1.f)};
}
__device__ __forceinline__ v2f sigm2(v2f x){
  v2f y = x*0.5f;
  v2f y2 = y*y;
  v2f num = y*(y2 + 27.f);
  v2f den = y2*9.f + 27.f;
  v2f r = num * rcp2(den);
  v2f rc = (v2f){__builtin_amdgcn_fmed3f(r.x,-1.f,1.f),
                 __builtin_amdgcn_fmed3f(r.y,-1.f,1.f)};
  return rc*0.5f + 0.5f;
}
// scalar Pade tanh/sigm (non-critical kernels)
__device__ __forceinline__ float tanh_p(float x){
  float x2 = x*x;
  float r = (x*(27.f + x2)) * __builtin_amdgcn_rcpf(27.f + 9.f*x2);
  return fminf(fmaxf(r, -1.f), 1.f);
}
// pi permutation: physical packed position p (0..255) -> logical h column
__device__ __forceinline__ int pi_col(int p){
  return ((p>>5)<<5) + ((p&1)<<4) + ((p&31)>>1);
}
__device__ __forceinline__ v8i ld32(const void* p){
  uint4 lo = *(const uint4*)p;
  uint4 hi = *(const uint4*)((const char*)p + 16);
  v8i r;
  r[0]=(int)lo.x; r[1]=(int)lo.y; r[2]=(int)lo.z; r[3]=(int)lo.w;
  r[4]=(int)hi.x; r[5]=(int)hi.y; r[6]=(int)hi.z; r[7]=(int)hi.w;
  return r;
}
// fp4 e2m1 encode of x (magnitudes {0,.5,1,1.5,2,3,4,6})
__device__ __forceinline__ unsigned f2fp4(float x){
  unsigned s = (x < 0.f) ? 8u : 0u;
  float a = fabsf(x);
  unsigned m;
  if      (a < 0.25f) m=0u; else if (a < 0.75f) m=1u;
  else if (a < 1.25f) m=2u; else if (a < 1.75f) m=3u;
  else if (a < 2.5f ) m=4u; else if (a < 3.5f ) m=5u;
  else if (a < 5.f  ) m=6u; else m=7u;
  return s|m;
}
// f32x4 -> packed fp8 dword
__device__ __forceinline__ unsigned pk8(float a, float b, float c, float d){
  int w = __builtin_amdgcn_cvt_pk_fp8_f32(a, b, 0, 0);
  w     = __builtin_amdgcn_cvt_pk_fp8_f32(c, d, w, 1);
  return (unsigned)w;
}

// fp8 K=128 B-fragments for Wih (both dirs, 2048 gate cols)
__global__ __launch_bounds__(256) void prep_wih8_k(
    const float* __restrict__ Wa, const float* __restrict__ Wb,
    unsigned char* __restrict__ out)
{
  int idx = blockIdx.x*256 + threadIdx.x;      // 16384 threads
  int lane = idx & 63;
  int t2 = idx >> 6;                           // 0..255
  int ntile = t2 & 127;
  int kt = t2 >> 7;
  int n = ntile*16 + (lane&15);
  const float* W = (n < 1024) ? (Wa + (size_t)n*256) : (Wb + (size_t)(n-1024)*256);
  int k0 = kt*128 + (lane>>4)*32;
  unsigned words[8];
  #pragma unroll
  for (int e=0;e<8;++e)
    words[e] = pk8(W[k0+e*4], W[k0+e*4+1], W[k0+e*4+2], W[k0+e*4+3]);
  unsigned char* d = out + (size_t)idx*32;
  *(uint4*)(d)      = make_uint4(words[0], words[1], words[2], words[3]);
  *(uint4*)(d + 16) = make_uint4(words[4], words[5], words[6], words[7]);
}

// fp4 K=128 B-fragments for Whh (2 dirs), 16 B per lane, pre-scaled x64,
// k-order pi-permuted to match packed h layout.
__global__ __launch_bounds__(256) void prep_whh4_k(
    const float* __restrict__ Wf, const float* __restrict__ Wb,
    unsigned char* __restrict__ out)
{
  int idx = blockIdx.x*256 + threadIdx.x;      // 16384 threads
  int lane = idx & 63;
  int t2 = idx >> 6;                           // 0..255
  int ntile = t2 & 63;
  int kt = (t2>>6) & 1;
  int dir = t2 >> 7;
  const float* W = dir ? Wb : Wf;
  int n = ntile*16 + (lane&15);
  int kbase = kt*128 + (lane>>4)*32;
  const float* row = W + (size_t)n*256;
  unsigned words[4];
  #pragma unroll
  for (int d4=0;d4<4;++d4){
    unsigned acc = 0;
    #pragma unroll
    for (int j=0;j<8;++j){
      float v = row[pi_col(kbase + d4*8 + j)] * 64.f;
      acc |= f2fp4(v) << (4*j);
    }
    words[d4] = acc;
  }
  *(uint4*)(out + (size_t)idx*16) = make_uint4(words[0], words[1], words[2], words[3]);
}

// xw = x @ [Wih_f; Wih_b]^T + bias (fp8 MX MFMA, K=128), M=128 rows/block.
__global__ __launch_bounds__(256) void xw_gemm_k(
    const int* __restrict__ sent, const float* __restrict__ emb,
    const unsigned char* __restrict__ wihg, const int* __restrict__ lens,
    const float* __restrict__ bfv, const float* __restrict__ bbv,
    unsigned char* __restrict__ xw)
{
  int mt = blockIdx.x;                         // 0..511, 128 rows each
  if (((mt&3)<<7) >= lens[mt>>2]) return;      // tile fully beyond len
  __shared__ unsigned char A[128][272];        // fp8 x rows
  int tid = threadIdx.x;
  {
    int row = tid>>1, half = tid&1;
    int tok = sent[mt*128 + row];
    const float4* s = (const float4*)(emb + (size_t)tok*256 + half*128);
    unsigned char* drow = &A[row][half*128];
    #pragma unroll
    for (int c4=0; c4<8; ++c4){
      unsigned w0[4];
      #pragma unroll
      for (int u=0; u<4; ++u){
        float4 v = s[c4*4+u];
        w0[u] = pk8(v.x, v.y, v.z, v.w);
      }
      *(uint4*)(drow + c4*16) = make_uint4(w0[0], w0[1], w0[2], w0[3]);
    }
  }
  __syncthreads();
  int w = tid>>6, lane = tid&63, lr = lane&15, lq = lane>>4;
  #pragma unroll 1
  for (int i4=0; i4<4; ++i4){
    int dnv = w*4 + i4;
    int dn = dnv>>3, v = dnv&7;
    const float* bb = dn ? bbv : bfv;
    float bias[8];
    #pragma unroll
    for (int e=0;e<8;++e){
      int q = e>>1, s = e&1;
      bias[e] = bb[q*256 + v*32 + s*16 + lr];
    }
    #pragma unroll 1
    for (int mh=0; mh<2; ++mh){
      v4f acc[8][4];
      #pragma unroll
      for (int e=0;e<8;++e)
        #pragma unroll
        for (int mm=0;mm<4;++mm) acc[e][mm] = (v4f){0.f,0.f,0.f,0.f};
      #pragma unroll
      for (int kt=0;kt<2;++kt){
        v8i a0 = ld32(&A[mh*64 +  0 + lr][kt*128 + lq*32]);
        v8i a1 = ld32(&A[mh*64 + 16 + lr][kt*128 + lq*32]);
        v8i a2 = ld32(&A[mh*64 + 32 + lr][kt*128 + lq*32]);
        v8i a3 = ld32(&A[mh*64 + 48 + lr][kt*128 + lq*32]);
        #pragma unroll
        for (int e=0;e<8;++e){
          int q = e>>1, s = e&1;
          int ntile = dn*64 + q*16 + v*2 + s;
          v8i bfr = ld32(wihg + ((size_t)(kt*128 + ntile)*64 + lane)*32);
          acc[e][0] = __builtin_amdgcn_mfma_scale_f32_16x16x128_f8f6f4(
                        a0, bfr, acc[e][0], 0,0, 0,0x7f7f7f7f, 0,0x7f7f7f7f);
          acc[e][1] = __builtin_amdgcn_mfma_scale_f32_16x16x128_f8f6f4(
                        a1, bfr, acc[e][1], 0,0, 0,0x7f7f7f7f, 0,0x7f7f7f7f);
          acc[e][2] = __builtin_amdgcn_mfma_scale_f32_16x16x128_f8f6f4(
                        a2, bfr, acc[e][2], 0,0, 0,0x7f7f7f7f, 0,0x7f7f7f7f);
          acc[e][3] = __builtin_amdgcn_mfma_scale_f32_16x16x128_f8f6f4(
                        a3, bfr, acc[e][3], 0,0, 0,0x7f7f7f7f, 0,0x7f7f7f7f);
        }
      }
      #pragma unroll
      for (int mm=0;mm<4;++mm){
        #pragma unroll
        for (int j=0;j<4;++j){
          int row = mt*128 + mh*64 + mm*16 + lq*4 + j;
          unsigned lo = pk8(acc[0][mm][j]+bias[0], acc[1][mm][j]+bias[1],
                            acc[2][mm][j]+bias[2], acc[3][mm][j]+bias[3]);
          unsigned hi = pk8(acc[4][mm][j]+bias[4], acc[5][mm][j]+bias[5],
                            acc[6][mm][j]+bias[6], acc[7][mm][j]+bias[7]);
          *(uint2*)(xw + ((size_t)dn*65536 + row)*1024 + v*128 + lr*8)
              = make_uint2(lo, hi);
        }
      }
    }
  }
}

// Recurrence: 64 blocks x 512 threads; block = (dir, 4 seqs at A-rows {0,4,8,12}).
// Whh fp4 register-resident; h fp8 in LDS dbuf; packed v2f epilogue (v_pk_*);
// ONE raw barrier/step (lgkmcnt only); dir-specialized inner loops.
__global__ __launch_bounds__(512,2) void lstm_k(
    const unsigned char* __restrict__ xw,
    const unsigned char* __restrict__ whh4,
    const int* __restrict__ lens,
    unsigned char* __restrict__ hout)
{
  int bid = blockIdx.x, dir = bid>>5, grp = bid&31;
  int tid = threadIdx.x, w = tid>>6, lane = tid&63, lr = lane&15, lq = lane>>4;
  __shared__ unsigned char hbuf[2][16][272];
  __shared__ int tmax_s;
  for (int i=tid*4; i<2*16*272; i+=512*4) *(unsigned int*)(&((unsigned char*)hbuf)[i]) = 0u;
  if (tid==0){
    int mx=0;
    for (int i=0;i<4;++i){ int l = lens[grp*4+i]; mx = l>mx? l:mx; }
    tmax_s = mx;
  }
  // Whh fp4 fragments: wave w owns ntile = q*16 + w*2 + s
  v4i wreg[16];
  const unsigned char* wb = whh4 + (size_t)dir*131072;
  #pragma unroll
  for (int kt=0;kt<2;++kt){
    #pragma unroll
    for (int nt=0;nt<8;++nt){
      int ntile = (nt>>1)*16 + w*2 + (nt&1);
      uint4 t = *(const uint4*)(wb + ((size_t)(kt*64 + ntile)*64 + lane)*16);
      v4i r; r[0]=(int)t.x; r[1]=(int)t.y; r[2]=(int)t.z; r[3]=(int)t.w;
      wreg[kt*8+nt] = r;
    }
  }
  int seq = grp*4 + lq;
  int ln = lens[seq];
  v2f cc = (v2f){0.f, 0.f};
  const size_t dbase = (size_t)dir*65536;
  const unsigned char* xbase = xw + (dbase + (size_t)seq*T_)*1024 + w*128 + lr*8;
  unsigned char* hbase = hout + (dbase + (size_t)seq*T_)*256 + w*32 + lr*2;
  unsigned char* lw0 = &hbuf[1][lq*4][w*32 + lr*2];   // write target when cur=0
  unsigned char* lw1 = &hbuf[0][lq*4][w*32 + lr*2];
  const unsigned char* lr0 = &hbuf[0][lr][lq*32];     // read source when cur=0
  const unsigned char* lr1 = &hbuf[1][lr][lq*32];
  __syncthreads();
  int tmax = tmax_s;
  uint2 xv = *(const uint2*)(xbase + (size_t)(dir ? (ln-1) : 0)*1024);

  #define STEP_BODY(TE_EXPR, POS_EXPR)                                         \
    int cur = t&1;                                                             \
    int tn = (t+1<tmax)? t+1 : t;                                              \
    int te = (TE_EXPR);                                                        \
    uint2 xn = *(const uint2*)(xbase + ((size_t)te<<10));                      \
    const unsigned char* lrd = cur? lr1 : lr0;                                 \
    v4f acc[8];                                                                \
    _Pragma("unroll")                                                          \
    for (int nt=0;nt<8;++nt) acc[nt] = (v4f){0.f,0.f,0.f,0.f};                 \
    _Pragma("unroll")                                                          \
    for (int kt=0;kt<2;++kt){                                                  \
      v8i a = ld32(lrd + kt*128);                                              \
      _Pragma("unroll")                                                        \
      for (int nt=0;nt<8;++nt){                                                \
        v4i wv4 = wreg[kt*8+nt];                                               \
        v8i b; b[0]=wv4[0]; b[1]=wv4[1]; b[2]=wv4[2]; b[3]=wv4[3];             \
        b[4]=0; b[5]=0; b[6]=0; b[7]=0;                                        \
        acc[nt] = __builtin_amdgcn_mfma_scale_f32_16x16x128_f8f6f4(            \
                    a, b, acc[nt], 0, 4, 0, 0x7f7f7f7f, 0, 0x79797979);        \
      }                                                                        \
    }                                                                          \
    bool valid = t < ln;                                                       \
    int pos = (POS_EXPR);                                                      \
    v2f xi = cvt2<0>(xv.x), xf = cvt2<1>(xv.x);                                \
    v2f xg = cvt2<0>(xv.y), xo = cvt2<1>(xv.y);                                \
    v2f gi = (v2f){acc[0][0], acc[1][0]} + xi;                                 \
    v2f gf = (v2f){acc[2][0], acc[3][0]} + xf;                                 \
    v2f gg = (v2f){acc[4][0], acc[5][0]} + xg;                                 \
    v2f go = (v2f){acc[6][0], acc[7][0]} + xo;                                 \
    v2f iv = sigm2(gi), fv = sigm2(gf), gv = tanh2(gg), ov = sigm2(go);        \
    v2f cn = fv*cc + iv*gv;                                                    \
    v2f hn = ov*tanh2(cn);                                                     \
    int hp = __builtin_amdgcn_cvt_pk_fp8_f32(hn.x, hn.y, 0, 0);                \
    unsigned short hu = valid ? (unsigned short)(hp & 0xffff) : (unsigned short)0; \
    if (valid){                                                                \
      cc = cn;                                                                 \
      *(unsigned short*)(cur? lw1 : lw0) = hu;                                 \
    }                                                                          \
    *(unsigned short*)(hbase + ((size_t)pos<<8)) = hu;                         \
    xv = xn;                                                                   \
    asm volatile("s_waitcnt lgkmcnt(0)" ::: "memory");                         \
    __builtin_amdgcn_s_barrier();                                              \
    __builtin_amdgcn_sched_barrier(0);

  if (dir == 0){
    for (int t=0; t<tmax; ++t){
      STEP_BODY(tn, t)
    }
  } else {
    for (int t=0; t<tmax; ++t){
      STEP_BODY((tn<ln)? (ln-1-tn) : tn, valid? (ln-1-t) : t)
    }
  }
  #undef STEP_BODY
}

// em = [h_f, h_b] @ Wout^T + b_out. Coalesced: 16-lane group per 256B row.
__global__ __launch_bounds__(256) void em_k(
    const unsigned char* __restrict__ hout,
    const float* __restrict__ Wout, const float* __restrict__ bout,
    const int* __restrict__ lens,
    float* __restrict__ em)
{
  __shared__ float Ws[9*512];
  for (int i=threadIdx.x;i<9*512;i+=256){
    int k = i>>9, p = i&511;
    int d = p>>8, pp = p&255;
    Ws[i] = Wout[k*512 + d*256 + pi_col(pp)];
  }
  __syncthreads();
  int wv = blockIdx.x*4 + (threadIdx.x>>6);
  int lane = threadIdx.x & 63;
  int g = lane>>4, r = lane&15;
  int m = wv*4 + g;
  const unsigned char* hf = hout + (size_t)m*256 + r*16;
  const unsigned char* hb = hout + ((size_t)65536 + m)*256 + r*16;
  uint4 vf = *(const uint4*)hf;
  uint4 vb = *(const uint4*)hb;
  float xf[16], xb[16];
  {
    v2f d0=cvt2<0>(vf.x), d1=cvt2<1>(vf.x), d2=cvt2<0>(vf.y), d3=cvt2<1>(vf.y);
    v2f d4=cvt2<0>(vf.z), d5=cvt2<1>(vf.z), d6=cvt2<0>(vf.w), d7=cvt2<1>(vf.w);
    xf[0]=d0.x; xf[1]=d0.y; xf[2]=d1.x; xf[3]=d1.y;
    xf[4]=d2.x; xf[5]=d2.y; xf[6]=d3.x; xf[7]=d3.y;
    xf[8]=d4.x; xf[9]=d4.y; xf[10]=d5.x; xf[11]=d5.y;
    xf[12]=d6.x; xf[13]=d6.y; xf[14]=d7.x; xf[15]=d7.y;
  }
  {
    v2f d0=cvt2<0>(vb.x), d1=cvt2<1>(vb.x), d2=cvt2<0>(vb.y), d3=cvt2<1>(vb.y);
    v2f d4=cvt2<0>(vb.z), d5=cvt2<1>(vb.z), d6=cvt2<0>(vb.w), d7=cvt2<1>(vb.w);
    xb[0]=d0.x; xb[1]=d0.y; xb[2]=d1.x; xb[3]=d1.y;
    xb[4]=d2.x; xb[5]=d2.y; xb[6]=d3.x; xb[7]=d3.y;
    xb[8]=d4.x; xb[9]=d4.y; xb[10]=d5.x; xb[11]=d5.y;
    xb[12]=d6.x; xb[13]=d6.y; xb[14]=d7.x; xb[15]=d7.y;
  }
  float a[9];
  #pragma unroll
  for (int k=0;k<9;++k){
    float s = 0.f;
    #pragma unroll
    for (int e=0;e<16;++e)
      s += xf[e]*Ws[k*512 + r*16 + e] + xb[e]*Ws[k*512 + 256 + r*16 + e];
    a[k]=s;
  }
  #pragma unroll
  for (int k=0;k<9;++k){
    #pragma unroll
    for (int off=8; off; off>>=1) a[k] += __shfl_xor(a[k], off, 64);
  }
  int b = m>>9, t = m&511;
  if (r==0 && t < lens[b]){
    float* d = em + (size_t)m*9;
    #pragma unroll
    for (int k=0;k<9;++k) d[k] = a[k] + bout[k];
  }
}

// CRF: one wave per sequence.
__global__ __launch_bounds__(256) void crf_k(
    const float* __restrict__ em, const int* __restrict__ tags,
    const int* __restrict__ lens, const float* __restrict__ startv,
    const float* __restrict__ endv, const float* __restrict__ trans,
    float* __restrict__ out)
{
  int wid = blockIdx.x*4 + (threadIdx.x>>6);
  int lane = threadIdx.x & 63;
  const float* e = em + (size_t)wid*T_*9;
  const int* tg = tags + (size_t)wid*T_;
  int L = lens[wid];
  float p = 0.f;
  for (int t = 1+lane; t < L; t += 64)
    p += trans[tg[t-1]*9 + tg[t]] + e[(size_t)t*9 + tg[t]];
  if (lane==0) p += startv[tg[0]] + e[tg[0]] + endv[tg[L-1]];
  #pragma unroll
  for (int off=32; off; off>>=1) p += __shfl_xor(p, off, 64);
  float tcol[9];
  #pragma unroll
  for (int i=0;i<9;++i) tcol[i] = (lane<9) ? trans[i*9 + lane] : 0.f;
  float alpha = (lane<9) ? (startv[lane] + e[lane]) : -1e30f;
  for (int t=1; t<L; ++t){
    float vs[9]; float mx = -1e30f;
    #pragma unroll
    for (int i=0;i<9;++i){
      float ai = __shfl(alpha, i, 64);
      vs[i] = ai + tcol[i];
      mx = fmaxf(mx, vs[i]);
    }
    float s = 0.f;
    #pragma unroll
    for (int i=0;i<9;++i) s += __expf(vs[i]-mx);
    float na = mx + __logf(s) + ((lane<9)? e[(size_t)t*9+lane] : 0.f);
    alpha = (lane<9) ? na : -1e30f;
  }
  float v = (lane<9) ? (alpha + endv[lane]) : -1e30f;
  float mx = v;
  #pragma unroll
  for (int off=32; off; off>>=1) mx = fmaxf(mx, __shfl_xor(mx, off, 64));
  float s = __expf(v-mx);
  #pragma unroll
  for (int off=32; off; off>>=1) s += __shfl_xor(s, off, 64);
  float logZ = mx + __logf(s);
  if (lane==0) atomicAdd(out, p - logZ);
}

extern "C" void kernel_launch(void* const* d_in, const int* in_sizes, int n_in,
                              void* d_out, int out_size, void* d_ws, size_t ws_size,
                              hipStream_t stream)
{
  const int*   sent  = (const int*)d_in[0];
  const int*   tags  = (const int*)d_in[1];
  const int*   lens  = (const int*)d_in[2];
  const float* emb   = (const float*)d_in[3];
  const float* Wih_f = (const float*)d_in[4];
  const float* Whh_f = (const float*)d_in[5];
  const float* b_f   = (const float*)d_in[6];
  const float* Wih_b = (const float*)d_in[7];
  const float* Whh_b = (const float*)d_in[8];
  const float* b_b   = (const float*)d_in[9];
  const float* Wout  = (const float*)d_in[10];
  const float* bout  = (const float*)d_in[11];
  const float* startv= (const float*)d_in[12];
  const float* endv  = (const float*)d_in[13];
  const float* trans = (const float*)d_in[14];
  char* ws = (char*)d_ws;
  // layout (~171 MB): wihg8 0.5MB | whh4 0.25MB | xw 128MB | hout 32MB | em 2.25MB
  unsigned char* wihg8 = (unsigned char*)(ws);
  unsigned char* whh4  = (unsigned char*)(ws + (size_t)524288);
  unsigned char* xw    = (unsigned char*)(ws + (size_t)1048576);
  unsigned char* hout  = (unsigned char*)(ws + (size_t)135266304);
  float* em            = (float*)(ws + (size_t)168820736);
  float* outp = (float*)d_out;

  (void)hipMemsetAsync(outp, 0, sizeof(float), stream);
  prep_wih8_k<<<64, 256, 0, stream>>>(Wih_f, Wih_b, wihg8);
  prep_whh4_k<<<64, 256, 0, stream>>>(Whh_f, Whh_b, whh4);
  xw_gemm_k<<<512, 256, 0, stream>>>(sent, emb, wihg8, lens, b_f, b_b, xw);
  lstm_k<<<64, 512, 0, stream>>>(xw, whh4, lens, hout);
  em_k<<<4096, 256, 0, stream>>>(hout, Wout, bout, lens, em);
  crf_k<<<32, 256, 0, stream>>>(em, tags, lens, startv, endv, trans, outp);
}

// Round 10
// 705.138 us; speedup vs baseline: 3.9143x; 1.0018x over previous
//
#include <hip/hip_runtime.h>
#include <hip/hip_bf16.h>

typedef short v8s __attribute__((ext_vector_type(8)));
typedef int   v8i __attribute__((ext_vector_type(8)));
typedef int   v4i __attribute__((ext_vector_type(4)));
typedef float v4f __attribute__((ext_vector_type(4)));
typedef float v2f __attribute__((ext_vector_type(2)));

#define T_ 512

// HW fp8 (OCP e4m3fn) unpack; word-select must be a literal constant
template<int HI>
__device__ __forceinline__ v2f cvt2(unsigned int wsrc){
  return __builtin_amdgcn_cvt_pk_f32_fp8((int)wsrc, HI);
}
__device__ __forceinline__ v2f rcp2(v2f d){
  return (v2f){__builtin_amdgcn_rcpf(d.x), __builtin_amdgcn_rcpf(d.y)};
}
// packed Pade(3,2) tanh with med3 clamp (2 cells per call)
__device__ __forceinline__ v2f tanh2(v2f x){
  v2f x2 = x*x;
  v2f num = x*(x2 + 27.f);
  v2f den = x2*9.f + 27.f;
  v2f r = num * rcp2(den);
  return (v2f){__builtin_amdgcn_fmed3f(r.x,-1.f,1.f),
               __builtin_amdgcn_fmed3f(r.y,-1.f,1.f)};
}
__device__ __forceinline__ v2f sigm2(v2f x){
  v2f y = x*0.5f;
  v2f y2 = y*y;
  v2f num = y*(y2 + 27.f);
  v2f den = y2*9.f + 27.f;
  v2f r = num * rcp2(den);
  v2f rc = (v2f){__builtin_amdgcn_fmed3f(r.x,-1.f,1.f),
                 __builtin_amdgcn_fmed3f(r.y,-1.f,1.f)};
  return rc*0.5f + 0.5f;
}
// pi permutation: physical packed position p (0..255) -> logical h column
__device__ __forceinline__ int pi_col(int p){
  return ((p>>5)<<5) + ((p&1)<<4) + ((p&31)>>1);
}
__device__ __forceinline__ v8i ld32(const void* p){
  uint4 lo = *(const uint4*)p;
  uint4 hi = *(const uint4*)((const char*)p + 16);
  v8i r;
  r[0]=(int)lo.x; r[1]=(int)lo.y; r[2]=(int)lo.z; r[3]=(int)lo.w;
  r[4]=(int)hi.x; r[5]=(int)hi.y; r[6]=(int)hi.z; r[7]=(int)hi.w;
  return r;
}
// fp4 e2m1 encode of x (magnitudes {0,.5,1,1.5,2,3,4,6})
__device__ __forceinline__ unsigned f2fp4(float x){
  unsigned s = (x < 0.f) ? 8u : 0u;
  float a = fabsf(x);
  unsigned m;
  if      (a < 0.25f) m=0u; else if (a < 0.75f) m=1u;
  else if (a < 1.25f) m=2u; else if (a < 1.75f) m=3u;
  else if (a < 2.5f ) m=4u; else if (a < 3.5f ) m=5u;
  else if (a < 5.f  ) m=6u; else m=7u;
  return s|m;
}
// f32x4 -> packed fp8 dword
__device__ __forceinline__ unsigned pk8(float a, float b, float c, float d){
  int w = __builtin_amdgcn_cvt_pk_fp8_f32(a, b, 0, 0);
  w     = __builtin_amdgcn_cvt_pk_fp8_f32(c, d, w, 1);
  return (unsigned)w;
}

// fp8 K=128 B-fragments for Wih (both dirs, 2048 gate cols)
__global__ __launch_bounds__(256) void prep_wih8_k(
    const float* __restrict__ Wa, const float* __restrict__ Wb,
    unsigned char* __restrict__ out)
{
  int idx = blockIdx.x*256 + threadIdx.x;      // 16384 threads
  int lane = idx & 63;
  int t2 = idx >> 6;                           // 0..255
  int ntile = t2 & 127;
  int kt = t2 >> 7;
  int n = ntile*16 + (lane&15);
  const float* W = (n < 1024) ? (Wa + (size_t)n*256) : (Wb + (size_t)(n-1024)*256);
  int k0 = kt*128 + (lane>>4)*32;
  unsigned words[8];
  #pragma unroll
  for (int e=0;e<8;++e)
    words[e] = pk8(W[k0+e*4], W[k0+e*4+1], W[k0+e*4+2], W[k0+e*4+3]);
  unsigned char* d = out + (size_t)idx*32;
  *(uint4*)(d)      = make_uint4(words[0], words[1], words[2], words[3]);
  *(uint4*)(d + 16) = make_uint4(words[4], words[5], words[6], words[7]);
}

// fp4 K=128 B-fragments for Whh (2 dirs), 16 B per lane, pre-scaled x64,
// k-order pi-permuted to match packed h layout.
__global__ __launch_bounds__(256) void prep_whh4_k(
    const float* __restrict__ Wf, const float* __restrict__ Wb,
    unsigned char* __restrict__ out)
{
  int idx = blockIdx.x*256 + threadIdx.x;      // 16384 threads
  int lane = idx & 63;
  int t2 = idx >> 6;                           // 0..255
  int ntile = t2 & 63;
  int kt = (t2>>6) & 1;
  int dir = t2 >> 7;
  const float* W = dir ? Wb : Wf;
  int n = ntile*16 + (lane&15);
  int kbase = kt*128 + (lane>>4)*32;
  const float* row = W + (size_t)n*256;
  unsigned words[4];
  #pragma unroll
  for (int d4=0;d4<4;++d4){
    unsigned acc = 0;
    #pragma unroll
    for (int j=0;j<8;++j){
      float v = row[pi_col(kbase + d4*8 + j)] * 64.f;
      acc |= f2fp4(v) << (4*j);
    }
    words[d4] = acc;
  }
  *(uint4*)(out + (size_t)idx*16) = make_uint4(words[0], words[1], words[2], words[3]);
}

// xw = x @ [Wih_f; Wih_b]^T + bias (fp8 MX MFMA, K=128), M=128 rows/block.
__global__ __launch_bounds__(256) void xw_gemm_k(
    const int* __restrict__ sent, const float* __restrict__ emb,
    const unsigned char* __restrict__ wihg, const int* __restrict__ lens,
    const float* __restrict__ bfv, const float* __restrict__ bbv,
    unsigned char* __restrict__ xw)
{
  int mt = blockIdx.x;                         // 0..511, 128 rows each
  if (((mt&3)<<7) >= lens[mt>>2]) return;      // tile fully beyond len
  __shared__ unsigned char A[128][272];        // fp8 x rows
  int tid = threadIdx.x;
  {
    int row = tid>>1, half = tid&1;
    int tok = sent[mt*128 + row];
    const float4* s = (const float4*)(emb + (size_t)tok*256 + half*128);
    unsigned char* drow = &A[row][half*128];
    #pragma unroll
    for (int c4=0; c4<8; ++c4){
      unsigned w0[4];
      #pragma unroll
      for (int u=0; u<4; ++u){
        float4 v = s[c4*4+u];
        w0[u] = pk8(v.x, v.y, v.z, v.w);
      }
      *(uint4*)(drow + c4*16) = make_uint4(w0[0], w0[1], w0[2], w0[3]);
    }
  }
  __syncthreads();
  int w = tid>>6, lane = tid&63, lr = lane&15, lq = lane>>4;
  #pragma unroll 1
  for (int i4=0; i4<4; ++i4){
    int dnv = w*4 + i4;
    int dn = dnv>>3, v = dnv&7;
    const float* bb = dn ? bbv : bfv;
    float bias[8];
    #pragma unroll
    for (int e=0;e<8;++e){
      int q = e>>1, s = e&1;
      bias[e] = bb[q*256 + v*32 + s*16 + lr];
    }
    #pragma unroll 1
    for (int mh=0; mh<2; ++mh){
      v4f acc[8][4];
      #pragma unroll
      for (int e=0;e<8;++e)
        #pragma unroll
        for (int mm=0;mm<4;++mm) acc[e][mm] = (v4f){0.f,0.f,0.f,0.f};
      #pragma unroll
      for (int kt=0;kt<2;++kt){
        v8i a0 = ld32(&A[mh*64 +  0 + lr][kt*128 + lq*32]);
        v8i a1 = ld32(&A[mh*64 + 16 + lr][kt*128 + lq*32]);
        v8i a2 = ld32(&A[mh*64 + 32 + lr][kt*128 + lq*32]);
        v8i a3 = ld32(&A[mh*64 + 48 + lr][kt*128 + lq*32]);
        #pragma unroll
        for (int e=0;e<8;++e){
          int q = e>>1, s = e&1;
          int ntile = dn*64 + q*16 + v*2 + s;
          v8i bfr = ld32(wihg + ((size_t)(kt*128 + ntile)*64 + lane)*32);
          acc[e][0] = __builtin_amdgcn_mfma_scale_f32_16x16x128_f8f6f4(
                        a0, bfr, acc[e][0], 0,0, 0,0x7f7f7f7f, 0,0x7f7f7f7f);
          acc[e][1] = __builtin_amdgcn_mfma_scale_f32_16x16x128_f8f6f4(
                        a1, bfr, acc[e][1], 0,0, 0,0x7f7f7f7f, 0,0x7f7f7f7f);
          acc[e][2] = __builtin_amdgcn_mfma_scale_f32_16x16x128_f8f6f4(
                        a2, bfr, acc[e][2], 0,0, 0,0x7f7f7f7f, 0,0x7f7f7f7f);
          acc[e][3] = __builtin_amdgcn_mfma_scale_f32_16x16x128_f8f6f4(
                        a3, bfr, acc[e][3], 0,0, 0,0x7f7f7f7f, 0,0x7f7f7f7f);
        }
      }
      #pragma unroll
      for (int mm=0;mm<4;++mm){
        #pragma unroll
        for (int j=0;j<4;++j){
          int row = mt*128 + mh*64 + mm*16 + lq*4 + j;
          unsigned lo = pk8(acc[0][mm][j]+bias[0], acc[1][mm][j]+bias[1],
                            acc[2][mm][j]+bias[2], acc[3][mm][j]+bias[3]);
          unsigned hi = pk8(acc[4][mm][j]+bias[4], acc[5][mm][j]+bias[5],
                            acc[6][mm][j]+bias[6], acc[7][mm][j]+bias[7]);
          *(uint2*)(xw + ((size_t)dn*65536 + row)*1024 + v*128 + lr*8)
              = make_uint2(lo, hi);
        }
      }
    }
  }
}

// Recurrence: 64 blocks x 512 threads; block = (dir, 4 seqs at A-rows {0,4,8,12}).
// Whh fp4 in PADDED v8i registers (zero halves baked -> no per-MFMA operand
// construction); acc undef-init with xw folded into C-in row 0; h fp8 in LDS
// dbuf; ONE raw barrier/step (lgkmcnt only).
__global__ __launch_bounds__(512,2) void lstm_k(
    const unsigned char* __restrict__ xw,
    const unsigned char* __restrict__ whh4,
    const int* __restrict__ lens,
    unsigned char* __restrict__ hout)
{
  int bid = blockIdx.x, dir = bid>>5, grp = bid&31;
  int tid = threadIdx.x, w = tid>>6, lane = tid&63, lr = lane&15, lq = lane>>4;
  __shared__ unsigned char hbuf[2][16][272];
  __shared__ int tmax_s;
  for (int i=tid*4; i<2*16*272; i+=512*4) *(unsigned int*)(&((unsigned char*)hbuf)[i]) = 0u;
  if (tid==0){
    int mx=0;
    for (int i=0;i<4;++i){ int l = lens[grp*4+i]; mx = l>mx? l:mx; }
    tmax_s = mx;
  }
  // Whh fp4 fragments padded to v8i once (loop-invariant operand tuples)
  v8i wreg[16];
  const unsigned char* wb = whh4 + (size_t)dir*131072;
  #pragma unroll
  for (int kt=0;kt<2;++kt){
    #pragma unroll
    for (int nt=0;nt<8;++nt){
      int ntile = (nt>>1)*16 + w*2 + (nt&1);
      uint4 t = *(const uint4*)(wb + ((size_t)(kt*64 + ntile)*64 + lane)*16);
      v8i r;
      r[0]=(int)t.x; r[1]=(int)t.y; r[2]=(int)t.z; r[3]=(int)t.w;
      r[4]=0; r[5]=0; r[6]=0; r[7]=0;
      wreg[kt*8+nt] = r;
    }
  }
  int seq = grp*4 + lq;
  int ln = lens[seq];
  v2f cc = (v2f){0.f, 0.f};
  const size_t dbase = (size_t)dir*65536;
  const unsigned char* xbase = xw + (dbase + (size_t)seq*T_)*1024 + w*128 + lr*8;
  unsigned char* hbase = hout + (dbase + (size_t)seq*T_)*256 + w*32 + lr*2;
  unsigned char* lw0 = &hbuf[1][lq*4][w*32 + lr*2];   // write target when cur=0
  unsigned char* lw1 = &hbuf[0][lq*4][w*32 + lr*2];
  const unsigned char* lr0 = &hbuf[0][lr][lq*32];     // read source when cur=0
  const unsigned char* lr1 = &hbuf[1][lr][lq*32];
  __syncthreads();
  int tmax = tmax_s;
  uint2 xv = *(const uint2*)(xbase + (size_t)(dir ? (ln-1) : 0)*1024);

  #define STEP_BODY(TE_EXPR, POS_EXPR)                                         \
    int cur = t&1;                                                             \
    int tn = (t+1<tmax)? t+1 : t;                                              \
    int te = (TE_EXPR);                                                        \
    uint2 xn = *(const uint2*)(xbase + ((size_t)te<<10));                      \
    const unsigned char* lrd = cur? lr1 : lr0;                                 \
    /* decode this step's xw, fold into acc C-in (row 0); rows 1..3 undef */   \
    v2f xi = cvt2<0>(xv.x), xf = cvt2<1>(xv.x);                                \
    v2f xg = cvt2<0>(xv.y), xo = cvt2<1>(xv.y);                                \
    v4f acc[8];                                                                \
    _Pragma("unroll")                                                          \
    for (int nt=0;nt<8;++nt) asm("" : "=v"(acc[nt]));                          \
    acc[0][0] = xi.x; acc[1][0] = xi.y;                                        \
    acc[2][0] = xf.x; acc[3][0] = xf.y;                                        \
    acc[4][0] = xg.x; acc[5][0] = xg.y;                                        \
    acc[6][0] = xo.x; acc[7][0] = xo.y;                                        \
    _Pragma("unroll")                                                          \
    for (int kt=0;kt<2;++kt){                                                  \
      v8i a = ld32(lrd + kt*128);                                              \
      _Pragma("unroll")                                                        \
      for (int nt=0;nt<8;++nt)                                                 \
        acc[nt] = __builtin_amdgcn_mfma_scale_f32_16x16x128_f8f6f4(            \
                    a, wreg[kt*8+nt], acc[nt], 0, 4, 0, 0x7f7f7f7f, 0, 0x79797979); \
    }                                                                          \
    bool valid = t < ln;                                                       \
    int pos = (POS_EXPR);                                                      \
    v2f gi = (v2f){acc[0][0], acc[1][0]};                                      \
    v2f gf = (v2f){acc[2][0], acc[3][0]};                                      \
    v2f gg = (v2f){acc[4][0], acc[5][0]};                                      \
    v2f go = (v2f){acc[6][0], acc[7][0]};                                      \
    v2f iv = sigm2(gi), fv = sigm2(gf), gv = tanh2(gg), ov = sigm2(go);        \
    v2f cn = fv*cc + iv*gv;                                                    \
    v2f hn = ov*tanh2(cn);                                                     \
    int hp = __builtin_amdgcn_cvt_pk_fp8_f32(hn.x, hn.y, 0, 0);                \
    unsigned short hu = valid ? (unsigned short)(hp & 0xffff) : (unsigned short)0; \
    if (valid){                                                                \
      cc = cn;                                                                 \
      *(unsigned short*)(cur? lw1 : lw0) = hu;                                 \
    }                                                                          \
    *(unsigned short*)(hbase + ((size_t)pos<<8)) = hu;                         \
    xv = xn;                                                                   \
    asm volatile("s_waitcnt lgkmcnt(0)" ::: "memory");                         \
    __builtin_amdgcn_s_barrier();                                              \
    __builtin_amdgcn_sched_barrier(0);

  if (dir == 0){
    for (int t=0; t<tmax; ++t){
      STEP_BODY(tn, t)
    }
  } else {
    for (int t=0; t<tmax; ++t){
      STEP_BODY((tn<ln)? (ln-1-tn) : tn, valid? (ln-1-t) : t)
    }
  }
  #undef STEP_BODY
}

// em = [h_f, h_b] @ Wout^T + b_out. Coalesced: 16-lane group per 256B row.
__global__ __launch_bounds__(256) void em_k(
    const unsigned char* __restrict__ hout,
    const float* __restrict__ Wout, const float* __restrict__ bout,
    const int* __restrict__ lens,
    float* __restrict__ em)
{
  __shared__ float Ws[9*512];
  for (int i=threadIdx.x;i<9*512;i+=256){
    int k = i>>9, p = i&511;
    int d = p>>8, pp = p&255;
    Ws[i] = Wout[k*512 + d*256 + pi_col(pp)];
  }
  __syncthreads();
  int wv = blockIdx.x*4 + (threadIdx.x>>6);
  int lane = threadIdx.x & 63;
  int g = lane>>4, r = lane&15;
  int m = wv*4 + g;
  const unsigned char* hf = hout + (size_t)m*256 + r*16;
  const unsigned char* hb = hout + ((size_t)65536 + m)*256 + r*16;
  uint4 vf = *(const uint4*)hf;
  uint4 vb = *(const uint4*)hb;
  float xf[16], xb[16];
  {
    v2f d0=cvt2<0>(vf.x), d1=cvt2<1>(vf.x), d2=cvt2<0>(vf.y), d3=cvt2<1>(vf.y);
    v2f d4=cvt2<0>(vf.z), d5=cvt2<1>(vf.z), d6=cvt2<0>(vf.w), d7=cvt2<1>(vf.w);
    xf[0]=d0.x; xf[1]=d0.y; xf[2]=d1.x; xf[3]=d1.y;
    xf[4]=d2.x; xf[5]=d2.y; xf[6]=d3.x; xf[7]=d3.y;
    xf[8]=d4.x; xf[9]=d4.y; xf[10]=d5.x; xf[11]=d5.y;
    xf[12]=d6.x; xf[13]=d6.y; xf[14]=d7.x; xf[15]=d7.y;
  }
  {
    v2f d0=cvt2<0>(vb.x), d1=cvt2<1>(vb.x), d2=cvt2<0>(vb.y), d3=cvt2<1>(vb.y);
    v2f d4=cvt2<0>(vb.z), d5=cvt2<1>(vb.z), d6=cvt2<0>(vb.w), d7=cvt2<1>(vb.w);
    xb[0]=d0.x; xb[1]=d0.y; xb[2]=d1.x; xb[3]=d1.y;
    xb[4]=d2.x; xb[5]=d2.y; xb[6]=d3.x; xb[7]=d3.y;
    xb[8]=d4.x; xb[9]=d4.y; xb[10]=d5.x; xb[11]=d5.y;
    xb[12]=d6.x; xb[13]=d6.y; xb[14]=d7.x; xb[15]=d7.y;
  }
  float a[9];
  #pragma unroll
  for (int k=0;k<9;++k){
    float s = 0.f;
    #pragma unroll
    for (int e=0;e<16;++e)
      s += xf[e]*Ws[k*512 + r*16 + e] + xb[e]*Ws[k*512 + 256 + r*16 + e];
    a[k]=s;
  }
  #pragma unroll
  for (int k=0;k<9;++k){
    #pragma unroll
    for (int off=8; off; off>>=1) a[k] += __shfl_xor(a[k], off, 64);
  }
  int b = m>>9, t = m&511;
  if (r==0 && t < lens[b]){
    float* d = em + (size_t)m*9;
    #pragma unroll
    for (int k=0;k<9;++k) d[k] = a[k] + bout[k];
  }
}

// CRF: one wave per sequence.
__global__ __launch_bounds__(256) void crf_k(
    const float* __restrict__ em, const int* __restrict__ tags,
    const int* __restrict__ lens, const float* __restrict__ startv,
    const float* __restrict__ endv, const float* __restrict__ trans,
    float* __restrict__ out)
{
  int wid = blockIdx.x*4 + (threadIdx.x>>6);
  int lane = threadIdx.x & 63;
  const float* e = em + (size_t)wid*T_*9;
  const int* tg = tags + (size_t)wid*T_;
  int L = lens[wid];
  float p = 0.f;
  for (int t = 1+lane; t < L; t += 64)
    p += trans[tg[t-1]*9 + tg[t]] + e[(size_t)t*9 + tg[t]];
  if (lane==0) p += startv[tg[0]] + e[tg[0]] + endv[tg[L-1]];
  #pragma unroll
  for (int off=32; off; off>>=1) p += __shfl_xor(p, off, 64);
  float tcol[9];
  #pragma unroll
  for (int i=0;i<9;++i) tcol[i] = (lane<9) ? trans[i*9 + lane] : 0.f;
  float alpha = (lane<9) ? (startv[lane] + e[lane]) : -1e30f;
  for (int t=1; t<L; ++t){
    float vs[9]; float mx = -1e30f;
    #pragma unroll
    for (int i=0;i<9;++i){
      float ai = __shfl(alpha, i, 64);
      vs[i] = ai + tcol[i];
      mx = fmaxf(mx, vs[i]);
    }
    float s = 0.f;
    #pragma unroll
    for (int i=0;i<9;++i) s += __expf(vs[i]-mx);
    float na = mx + __logf(s) + ((lane<9)? e[(size_t)t*9+lane] : 0.f);
    alpha = (lane<9) ? na : -1e30f;
  }
  float v = (lane<9) ? (alpha + endv[lane]) : -1e30f;
  float mx = v;
  #pragma unroll
  for (int off=32; off; off>>=1) mx = fmaxf(mx, __shfl_xor(mx, off, 64));
  float s = __expf(v-mx);
  #pragma unroll
  for (int off=32; off; off>>=1) s += __shfl_xor(s, off, 64);
  float logZ = mx + __logf(s);
  if (lane==0) atomicAdd(out, p - logZ);
}

extern "C" void kernel_launch(void* const* d_in, const int* in_sizes, int n_in,
                              void* d_out, int out_size, void* d_ws, size_t ws_size,
                              hipStream_t stream)
{
  const int*   sent  = (const int*)d_in[0];
  const int*   tags  = (const int*)d_in[1];
  const int*   lens  = (const int*)d_in[2];
  const float* emb   = (const float*)d_in[3];
  const float* Wih_f = (const float*)d_in[4];
  const float* Whh_f = (const float*)d_in[5];
  const float* b_f   = (const float*)d_in[6];
  const float* Wih_b = (const float*)d_in[7];
  const float* Whh_b = (const float*)d_in[8];
  const float* b_b   = (const float*)d_in[9];
  const float* Wout  = (const float*)d_in[10];
  const float* bout  = (const float*)d_in[11];
  const float* startv= (const float*)d_in[12];
  const float* endv  = (const float*)d_in[13];
  const float* trans = (const float*)d_in[14];
  char* ws = (char*)d_ws;
  // layout (~171 MB): wihg8 0.5MB | whh4 0.25MB | xw 128MB | hout 32MB | em 2.25MB
  unsigned char* wihg8 = (unsigned char*)(ws);
  unsigned char* whh4  = (unsigned char*)(ws + (size_t)524288);
  unsigned char* xw    = (unsigned char*)(ws + (size_t)1048576);
  unsigned char* hout  = (unsigned char*)(ws + (size_t)135266304);
  float* em            = (float*)(ws + (size_t)168820736);
  float* outp = (float*)d_out;

  (void)hipMemsetAsync(outp, 0, sizeof(float), stream);
  prep_wih8_k<<<64, 256, 0, stream>>>(Wih_f, Wih_b, wihg8);
  prep_whh4_k<<<64, 256, 0, stream>>>(Whh_f, Whh_b, whh4);
  xw_gemm_k<<<512, 256, 0, stream>>>(sent, emb, wihg8, lens, b_f, b_b, xw);
  lstm_k<<<64, 512, 0, stream>>>(xw, whh4, lens, hout);
  em_k<<<4096, 256, 0, stream>>>(hout, Wout, bout, lens, em);
  crf_k<<<32, 256, 0, stream>>>(em, tags, lens, startv, endv, trans, outp);
}